// Round 2
// baseline (3558.306 us; speedup 1.0000x reference)
//
#include <hip/hip_runtime.h>
#include <hip/hip_bf16.h>

typedef _Float16 f16x8 __attribute__((ext_vector_type(8)));
typedef float f32x4 __attribute__((ext_vector_type(4)));
typedef unsigned short us8 __attribute__((ext_vector_type(8)));
typedef unsigned short us4 __attribute__((ext_vector_type(4)));

#define N_ 2048
#define B_ 16
#define T_ 12
#define DH 64
#define CC 65      // DIN + DOUT
#define NC 1040    // B_*CC
#define NCP 1088   // padded col count (17*64)
#define KI 195     // K*CC
#define EDIM 10
#define ASCALE 1024.0f
#define AINV (1.0f / 1024.0f)

// ---------------- A = softmax(relu(E E^T)) rowwise, f16 scaled by 1024 ----------------
__global__ __launch_bounds__(256) void k_compA(const float* __restrict__ emb,
                                               _Float16* __restrict__ A) {
    int n = blockIdx.x, tid = threadIdx.x;
    float en[EDIM];
#pragma unroll
    for (int d = 0; d < EDIM; ++d) en[d] = emb[n * EDIM + d];
    float v[8], mx = -1e30f;
#pragma unroll
    for (int j = 0; j < 8; ++j) {
        int m = tid + j * 256;
        float acc = 0.f;
#pragma unroll
        for (int d = 0; d < EDIM; ++d) acc = fmaf(en[d], emb[m * EDIM + d], acc);
        acc = fmaxf(acc, 0.f);
        v[j] = acc; mx = fmaxf(mx, acc);
    }
    __shared__ float red[256];
    red[tid] = mx; __syncthreads();
    for (int s = 128; s > 0; s >>= 1) { if (tid < s) red[tid] = fmaxf(red[tid], red[tid + s]); __syncthreads(); }
    mx = red[0]; __syncthreads();
    float se = 0.f;
#pragma unroll
    for (int j = 0; j < 8; ++j) { v[j] = __expf(v[j] - mx); se += v[j]; }
    red[tid] = se; __syncthreads();
    for (int s = 128; s > 0; s >>= 1) { if (tid < s) red[tid] += red[tid + s]; __syncthreads(); }
    float inv = ASCALE / red[0];
#pragma unroll
    for (int j = 0; j < 8; ++j) A[(long)n * N_ + tid + j * 256] = (_Float16)(v[j] * inv);
}

// ---------------- per-node GRU weights (f16) + biases (f32) ----------------
__global__ __launch_bounds__(256) void k_build(const float* __restrict__ emb,
        const float* __restrict__ gw, const float* __restrict__ gb,
        const float* __restrict__ uw, const float* __restrict__ ub,
        _Float16* __restrict__ Gw, float* __restrict__ Gb,
        _Float16* __restrict__ Uw, float* __restrict__ Ub) {
    const int G1 = 2048 * KI * 128;           // 51,118,080
    const int G2 = 2048 * KI * 64;            // 25,559,040
    const int G3 = 2048 * 128, G4 = 2048 * 64;
    int total = G1 + G2 + G3 + G4;
    for (int idx = blockIdx.x * 256 + threadIdx.x; idx < total; idx += gridDim.x * 256) {
        if (idx < G1) {
            int n = idx / (KI * 128), rem = idx % (KI * 128);
            float a = 0.f;
#pragma unroll
            for (int d = 0; d < EDIM; ++d) a = fmaf(emb[n * EDIM + d], gw[d * (KI * 128) + rem], a);
            Gw[idx] = (_Float16)a;
        } else if (idx < G1 + G2) {
            int i2 = idx - G1;
            int n = i2 / (KI * 64), rem = i2 % (KI * 64);
            float a = 0.f;
#pragma unroll
            for (int d = 0; d < EDIM; ++d) a = fmaf(emb[n * EDIM + d], uw[d * (KI * 64) + rem], a);
            Uw[i2] = (_Float16)a;
        } else if (idx < G1 + G2 + G3) {
            int i3 = idx - G1 - G2;
            int n = i3 >> 7, o = i3 & 127;
            float a = 0.f;
#pragma unroll
            for (int d = 0; d < EDIM; ++d) a = fmaf(emb[n * EDIM + d], gb[d * 128 + o], a);
            Gb[i3] = a;
        } else {
            int i4 = idx - G1 - G2 - G3;
            int n = i4 >> 6, o = i4 & 63;
            float a = 0.f;
#pragma unroll
            for (int d = 0; d < EDIM; ++d) a = fmaf(emb[n * EDIM + d], ub[d * 64 + o], a);
            Ub[i4] = a;
        }
    }
}

// ---------------- build X^T (c,m) f16 for the graph-conv GEMMs ----------------
// c = b*65 + i : i==0 -> x_t[b,m];  i>=1 -> h[b,m,i-1] (UPD: z*h). rows 1040..1087 zero.
template <int UPD>
__global__ __launch_bounds__(256) void k_prep(const float* __restrict__ src,
        const float* __restrict__ h, const float* __restrict__ z,
        int t, _Float16* __restrict__ XT) {
    int x = blockIdx.x;   // m-tile (64)
    int y = blockIdx.y;   // 0..15: b, 16: x-cols + pad
    int tid = threadIdx.x;
    if (y < 16) {
        __shared__ float Ls[64][65];
        int b = y, m0 = x * 64;
        int j = tid & 63, rq = tid >> 6;
        for (int rr = 0; rr < 16; ++rr) {
            int rw = rq * 16 + rr;
            long base = ((long)b * N_ + m0 + rw) * DH + j;
            float val = h[base];
            if (UPD) val *= z[base];
            Ls[rw][j] = val;
        }
        __syncthreads();
        int mm = tid & 63, jq = tid >> 6;
        for (int jj = 0; jj < 16; ++jj) {
            int jc = jq * 16 + jj;
            XT[(long)(b * CC + 1 + jc) * N_ + m0 + mm] = (_Float16)Ls[mm][jc];
        }
    } else {
        int m = x * 64 + (tid & 63);
        int cr = tid >> 6;
        for (int cc2 = 0; cc2 < 16; ++cc2) {
            int idx = cr * 16 + cc2;
            long c; float val;
            if (idx < 16) { c = (long)idx * CC; val = src[((long)idx * T_ + t) * N_ + m]; }
            else          { c = NC + (idx - 16); val = 0.f; }
            XT[c * N_ + m] = (_Float16)val;
        }
    }
}

// ---------------- D[n][c] = (1/1024) * sum_m A[n][m] * BT[c][m]; write DT[c][n] f16 ----------------
__global__ __launch_bounds__(256) void k_gemm(const _Float16* __restrict__ A,
        const _Float16* __restrict__ BT, _Float16* __restrict__ DT) {
    int bm = blockIdx.x;      // 0..31 row tiles
    int bc = blockIdx.y;      // 0..16 col tiles
    int tid = threadIdx.x;
    int wid = tid >> 6, lane = tid & 63;
    __shared__ __align__(16) _Float16 As[64][72];
    __shared__ __align__(16) _Float16 Bs[64][72];
    f32x4 acc[2][2] = {};
    int r0 = (wid & 1) * 32, c0 = (wid >> 1) * 32;
    int row_g = bm * 64, col_g = bc * 64;
    for (int kt = 0; kt < 32; ++kt) {
        int k0 = kt * 64;
        us8 ar[2], br[2];
#pragma unroll
        for (int p = 0; p < 2; ++p) {
            int idx = p * 256 + tid;
            int rw = idx >> 3, seg = idx & 7;
            ar[p] = *(const us8*)(A + (long)(row_g + rw) * N_ + k0 + seg * 8);
            br[p] = *(const us8*)(BT + (long)(col_g + rw) * N_ + k0 + seg * 8);
        }
        __syncthreads();
#pragma unroll
        for (int p = 0; p < 2; ++p) {
            int idx = p * 256 + tid;
            int rw = idx >> 3, seg = idx & 7;
            *(us8*)&As[rw][seg * 8] = ar[p];
            *(us8*)&Bs[rw][seg * 8] = br[p];
        }
        __syncthreads();
#pragma unroll
        for (int kk = 0; kk < 64; kk += 32) {
            int kb = kk + (lane >> 4) * 8;
            f16x8 af[2], bf[2];
            af[0] = *(const f16x8*)&As[r0 + (lane & 15)][kb];
            af[1] = *(const f16x8*)&As[r0 + 16 + (lane & 15)][kb];
            bf[0] = *(const f16x8*)&Bs[c0 + (lane & 15)][kb];
            bf[1] = *(const f16x8*)&Bs[c0 + 16 + (lane & 15)][kb];
#pragma unroll
            for (int rt = 0; rt < 2; ++rt)
#pragma unroll
                for (int ct = 0; ct < 2; ++ct)
                    acc[rt][ct] = __builtin_amdgcn_mfma_f32_16x16x32_f16(af[rt], bf[ct], acc[rt][ct], 0, 0, 0);
        }
        __syncthreads();
    }
#pragma unroll
    for (int rt = 0; rt < 2; ++rt)
#pragma unroll
        for (int ct = 0; ct < 2; ++ct) {
            int cg = col_g + c0 + ct * 16 + (lane & 15);
            int ng = row_g + r0 + rt * 16 + ((lane >> 4) << 2);
            us4 pk;
#pragma unroll
            for (int q = 0; q < 4; ++q) pk[q] = __builtin_bit_cast(unsigned short, (_Float16)(acc[rt][ct][q] * AINV));
            *(us4*)(DT + (long)cg * N_ + ng) = pk;
        }
}

// ---------------- gate apply: zr = sigmoid(xg . Gw + Gb) -> z, r ----------------
__global__ __launch_bounds__(256) void k_apply_gate(const float* __restrict__ src,
        const float* __restrict__ h, const _Float16* __restrict__ Y1T,
        const _Float16* __restrict__ Y2T, const _Float16* __restrict__ Gw,
        const float* __restrict__ Gb, int t,
        float* __restrict__ z, float* __restrict__ r) {
    int n = blockIdx.x, tid = threadIdx.x;
    __shared__ float xgf[16 * KI];
    for (int idx = tid; idx < 16 * KI; idx += 256) {
        int b = idx / KI, kk = idx % KI;
        int k = kk / CC, i = kk % CC;
        float ih = (i == 0) ? src[((long)b * T_ + t) * N_ + n]
                            : h[((long)b * N_ + n) * DH + (i - 1)];
        float val;
        if (k == 0)      val = ih;
        else if (k == 1) val = (float)Y1T[(long)(b * CC + i) * N_ + n];
        else             val = 2.f * (float)Y2T[(long)(b * CC + i) * N_ + n] - ih;
        xgf[idx] = val;
    }
    __syncthreads();
    int o = tid & 127, bg = tid >> 7;
    float acc[8];
    float bias = Gb[(long)n * 128 + o];
#pragma unroll
    for (int q = 0; q < 8; ++q) acc[q] = bias;
    const _Float16* W = Gw + (long)n * (KI * 128) + o;
    for (int kk = 0; kk < KI; ++kk) {
        float w = (float)W[(long)kk * 128];
#pragma unroll
        for (int q = 0; q < 8; ++q) acc[q] = fmaf(xgf[(bg * 8 + q) * KI + kk], w, acc[q]);
    }
#pragma unroll
    for (int q = 0; q < 8; ++q) {
        int b = bg * 8 + q;
        float sv = 1.f / (1.f + __expf(-acc[q]));
        long base = ((long)b * N_ + n) * DH;
        if (o < 64) z[base + o] = sv; else r[base + (o - 64)] = sv;
    }
}

// ---------------- update apply: hc = tanh(.); h = r*h + (1-r)*hc; states[t] = h ----------------
__global__ __launch_bounds__(256) void k_apply_update(const float* __restrict__ src,
        float* __restrict__ h, const _Float16* __restrict__ Y1T,
        const _Float16* __restrict__ Y2T, const _Float16* __restrict__ Uw,
        const float* __restrict__ Ub, const float* __restrict__ z,
        const float* __restrict__ rb, int t, _Float16* __restrict__ states) {
    int n = blockIdx.x, tid = threadIdx.x;
    __shared__ float xgf[16 * KI];
    for (int idx = tid; idx < 16 * KI; idx += 256) {
        int b = idx / KI, kk = idx % KI;
        int k = kk / CC, i = kk % CC;
        float ih;
        if (i == 0) ih = src[((long)b * T_ + t) * N_ + n];
        else {
            long base = ((long)b * N_ + n) * DH + (i - 1);
            ih = h[base] * z[base];
        }
        float val;
        if (k == 0)      val = ih;
        else if (k == 1) val = (float)Y1T[(long)(b * CC + i) * N_ + n];
        else             val = 2.f * (float)Y2T[(long)(b * CC + i) * N_ + n] - ih;
        xgf[idx] = val;
    }
    __syncthreads();
    int o = tid & 63, bg = tid >> 6;
    float acc[4];
    float bias = Ub[(long)n * 64 + o];
#pragma unroll
    for (int q = 0; q < 4; ++q) acc[q] = bias;
    const _Float16* W = Uw + (long)n * (KI * 64) + o;
    for (int kk = 0; kk < KI; ++kk) {
        float w = (float)W[(long)kk * 64];
#pragma unroll
        for (int q = 0; q < 4; ++q) acc[q] = fmaf(xgf[(bg * 4 + q) * KI + kk], w, acc[q]);
    }
#pragma unroll
    for (int q = 0; q < 4; ++q) {
        int b = bg * 4 + q;
        long base = ((long)b * N_ + n) * DH + o;
        float hc = tanhf(acc[q]);
        float rv = rb[base], hv = h[base];
        float hn = rv * hv + (1.f - rv) * hc;
        h[base] = hn;
        states[(((long)b * T_ + t) * N_ + n) * DH + o] = (_Float16)hn;
    }
}

// ---------------- fused transformer (only t = T-1 output needed) ----------------
__global__ __launch_bounds__(256) void k_attn(const _Float16* __restrict__ states,
        const float* __restrict__ Wi, const float* __restrict__ bi,
        const float* __restrict__ Wo, const float* __restrict__ bo,
        float* __restrict__ o1) {
    __shared__ _Float16 Wt[64][192];    // [e][col] of attn_in_w^T
    __shared__ _Float16 WoT[64][64];
    __shared__ float bis[192], bos[64];
    __shared__ float Xs[4][12][65];
    __shared__ float outs[4][64];
    int tid = threadIdx.x;
    for (int idx = tid; idx < 64 * 192; idx += 256) { int e = idx / 192, j = idx % 192; Wt[e][j] = (_Float16)Wi[j * 64 + e]; }
    for (int idx = tid; idx < 64 * 64; idx += 256) { int e = idx >> 6, j = idx & 63; WoT[e][j] = (_Float16)Wo[j * 64 + e]; }
    for (int idx = tid; idx < 192; idx += 256) bis[idx] = bi[idx];
    for (int idx = tid; idx < 64; idx += 256) bos[idx] = bo[idx];
    __syncthreads();
    int w = tid >> 6, j = tid & 63;
    float divj = __powf(10000.f, -(float)(j & ~1) / 64.f);
    for (int it = 0; it < 8; ++it) {
        int m = blockIdx.x * 4 + w + it * 4096;
        int b = m >> 11, n = m & 2047;
#pragma unroll
        for (int tt = 0; tt < 12; ++tt) {
            float xv = (float)states[(((long)b * T_ + tt) * N_ + n) * DH + j];
            float ang = (float)tt * divj;
            xv += (j & 1) ? __cosf(ang) : __sinf(ang);
            Xs[w][tt][j] = xv;
        }
        __syncthreads();
        float kreg[12], vreg[12];
#pragma unroll
        for (int tt = 0; tt < 12; ++tt) { kreg[tt] = bis[64 + j]; vreg[tt] = bis[128 + j]; }
        float qreg = bis[j];
        for (int e = 0; e < 64; ++e) {
            float wk = (float)Wt[e][64 + j], wv = (float)Wt[e][128 + j];
#pragma unroll
            for (int tt = 0; tt < 12; ++tt) {
                float xv = Xs[w][tt][e];
                kreg[tt] = fmaf(xv, wk, kreg[tt]);
                vreg[tt] = fmaf(xv, wv, vreg[tt]);
            }
            qreg = fmaf(Xs[w][11][e], (float)Wt[e][j], qreg);
        }
        float att[12], mx = -1e30f;
#pragma unroll
        for (int s = 0; s < 12; ++s) {
            float p = qreg * kreg[s];
            p += __shfl_xor(p, 1); p += __shfl_xor(p, 2);
            p += __shfl_xor(p, 4); p += __shfl_xor(p, 8);
            p *= 0.25f;                       // 1/sqrt(16)
            att[s] = p; mx = fmaxf(mx, p);
        }
        float se = 0.f;
#pragma unroll
        for (int s = 0; s < 12; ++s) { att[s] = __expf(att[s] - mx); se += att[s]; }
        float inv = 1.f / se, ov = 0.f;
#pragma unroll
        for (int s = 0; s < 12; ++s) ov = fmaf(att[s] * inv, vreg[s], ov);
        outs[w][j] = ov;
        __syncthreads();
        float oo = bos[j];
        for (int e = 0; e < 64; ++e) oo = fmaf(outs[w][e], (float)WoT[e][j], oo);
        o1[(long)m * DH + j] = oo;
        __syncthreads();
    }
}

// ---------------- output head ----------------
__global__ __launch_bounds__(256) void k_final(const float* __restrict__ o1,
        const float* __restrict__ hT, const float* __restrict__ cw,
        const float* __restrict__ convw, const float* __restrict__ convb,
        float* __restrict__ out) {
    __shared__ float Ws[12 * 3 * 64];
    __shared__ float cbs[12];
    int tid = threadIdx.x;
    for (int idx = tid; idx < 12 * 3 * 64; idx += 256) Ws[idx] = convw[idx];
    if (tid < 12) cbs[tid] = convb[tid];
    __syncthreads();
    float c0 = cw[0], c1 = cw[1], c2 = cw[2];
    int g = tid >> 6, j = tid & 63;
    int bn = blockIdx.x * 4 + g;
    int b = bn >> 11, n = bn & 2047;
    float x1 = o1[(long)bn * DH + j];
    float x3 = hT[(long)bn * DH + j];
    float myout = 0.f;
#pragma unroll
    for (int oc = 0; oc < 12; ++oc) {
        float p = x1 * c0 * Ws[(oc * 3 + 0) * 64 + j]
                + x3 * (c1 * Ws[(oc * 3 + 1) * 64 + j] + c2 * Ws[(oc * 3 + 2) * 64 + j]);
        p += __shfl_xor(p, 1); p += __shfl_xor(p, 2); p += __shfl_xor(p, 4);
        p += __shfl_xor(p, 8); p += __shfl_xor(p, 16); p += __shfl_xor(p, 32);
        if (j == oc) myout = p + cbs[oc];
    }
    if (j < 12) out[((long)b * 12 + j) * N_ + n] = myout;
}

extern "C" void kernel_launch(void* const* d_in, const int* in_sizes, int n_in,
                              void* d_out, int out_size, void* d_ws, size_t ws_size,
                              hipStream_t stream) {
    const float* src    = (const float*)d_in[0];
    const float* emb    = (const float*)d_in[2];
    const float* gate_w = (const float*)d_in[3];
    const float* gate_b = (const float*)d_in[4];
    const float* upd_w  = (const float*)d_in[5];
    const float* upd_b  = (const float*)d_in[6];
    const float* a_in_w = (const float*)d_in[7];
    const float* a_in_b = (const float*)d_in[8];
    const float* a_out_w= (const float*)d_in[9];
    const float* a_out_b= (const float*)d_in[10];
    const float* chan_w = (const float*)d_in[11];
    const float* conv_w = (const float*)d_in[12];
    const float* conv_b = (const float*)d_in[13];
    float* out = (float*)d_out;

    char* ws = (char*)d_ws;
    size_t off = 0;
    auto alloc = [&](size_t bytes) { char* p = ws + off; off += (bytes + 255) & ~size_t(255); return p; };
    _Float16* A   = (_Float16*)alloc((size_t)N_ * N_ * 2);
    _Float16* Gw  = (_Float16*)alloc((size_t)N_ * KI * 128 * 2);
    float*  Gb    = (float*) alloc((size_t)N_ * 128 * 4);
    _Float16* Uw  = (_Float16*)alloc((size_t)N_ * KI * 64 * 2);
    float*  Ub    = (float*) alloc((size_t)N_ * 64 * 4);
    _Float16* XT  = (_Float16*)alloc((size_t)NCP * N_ * 2);
    _Float16* Y1T = (_Float16*)alloc((size_t)NCP * N_ * 2);
    _Float16* Y2T = (_Float16*)alloc((size_t)NCP * N_ * 2);
    float*  h    = (float*) alloc((size_t)B_ * N_ * DH * 4);
    float*  zbuf = (float*) alloc((size_t)B_ * N_ * DH * 4);
    float*  rbuf = (float*) alloc((size_t)B_ * N_ * DH * 4);
    _Float16* st = (_Float16*)alloc((size_t)B_ * T_ * N_ * DH * 2);
    float*  o1   = (float*) alloc((size_t)B_ * N_ * DH * 4);
    if (off > ws_size) return;   // workspace too small: bail (output stays poisoned)

    hipMemsetAsync(h, 0, (size_t)B_ * N_ * DH * 4, stream);
    k_compA<<<N_, 256, 0, stream>>>(emb, A);
    k_build<<<4096, 256, 0, stream>>>(emb, gate_w, gate_b, upd_w, upd_b, Gw, Gb, Uw, Ub);

    dim3 pgrid(32, 17), ggrid(32, 17);
    for (int t = 0; t < T_; ++t) {
        k_prep<0><<<pgrid, 256, 0, stream>>>(src, h, h, t, XT);
        k_gemm<<<ggrid, 256, 0, stream>>>(A, XT, Y1T);
        k_gemm<<<ggrid, 256, 0, stream>>>(A, Y1T, Y2T);
        k_apply_gate<<<N_, 256, 0, stream>>>(src, h, Y1T, Y2T, Gw, Gb, t, zbuf, rbuf);
        k_prep<1><<<pgrid, 256, 0, stream>>>(src, h, zbuf, t, XT);
        k_gemm<<<ggrid, 256, 0, stream>>>(A, XT, Y1T);
        k_gemm<<<ggrid, 256, 0, stream>>>(A, Y1T, Y2T);
        k_apply_update<<<N_, 256, 0, stream>>>(src, h, Y1T, Y2T, Uw, Ub, zbuf, rbuf, t, st);
    }
    k_attn<<<1024, 256, 0, stream>>>(st, a_in_w, a_in_b, a_out_w, a_out_b, o1);
    k_final<<<8192, 256, 0, stream>>>(o1, h, chan_w, conv_w, conv_b, out);
}

// Round 3
// 3156.892 us; speedup vs baseline: 1.1272x; 1.1272x over previous
//
#include <hip/hip_runtime.h>
#include <hip/hip_bf16.h>

typedef _Float16 f16x8 __attribute__((ext_vector_type(8)));
typedef float f32x4 __attribute__((ext_vector_type(4)));
typedef unsigned short us8 __attribute__((ext_vector_type(8)));
typedef unsigned short us4 __attribute__((ext_vector_type(4)));

#define N_ 2048
#define B_ 16
#define T_ 12
#define DH 64
#define CC 65      // DIN + DOUT
#define NC 1040    // B_*CC
#define NCP 1088   // padded col count (17*64)
#define KI 195     // K*CC
#define EDIM 10
#define ASCALE 1024.0f
#define AINV (1.0f / 1024.0f)

// ---------------- A = softmax(relu(E E^T)) rowwise, f16 scaled by 1024 ----------------
__global__ __launch_bounds__(256) void k_compA(const float* __restrict__ emb,
                                               _Float16* __restrict__ A) {
    int n = blockIdx.x, tid = threadIdx.x;
    float en[EDIM];
#pragma unroll
    for (int d = 0; d < EDIM; ++d) en[d] = emb[n * EDIM + d];
    float v[8], mx = -1e30f;
#pragma unroll
    for (int j = 0; j < 8; ++j) {
        int m = tid + j * 256;
        float acc = 0.f;
#pragma unroll
        for (int d = 0; d < EDIM; ++d) acc = fmaf(en[d], emb[m * EDIM + d], acc);
        acc = fmaxf(acc, 0.f);
        v[j] = acc; mx = fmaxf(mx, acc);
    }
    __shared__ float red[256];
    red[tid] = mx; __syncthreads();
    for (int s = 128; s > 0; s >>= 1) { if (tid < s) red[tid] = fmaxf(red[tid], red[tid + s]); __syncthreads(); }
    mx = red[0]; __syncthreads();
    float se = 0.f;
#pragma unroll
    for (int j = 0; j < 8; ++j) { v[j] = __expf(v[j] - mx); se += v[j]; }
    red[tid] = se; __syncthreads();
    for (int s = 128; s > 0; s >>= 1) { if (tid < s) red[tid] += red[tid + s]; __syncthreads(); }
    float inv = ASCALE / red[0];
#pragma unroll
    for (int j = 0; j < 8; ++j) A[(long)n * N_ + tid + j * 256] = (_Float16)(v[j] * inv);
}

// ---------------- per-node GRU weights (f16) + biases (f32), outer-product form ----------------
// blocks [0,196): Gw halves; [196,294): Uw halves; [294,310): biases
__global__ __launch_bounds__(256) void k_build(const float* __restrict__ emb,
        const float* __restrict__ gw, const float* __restrict__ gb,
        const float* __restrict__ uw, const float* __restrict__ ub,
        _Float16* __restrict__ Gw, float* __restrict__ Gb,
        _Float16* __restrict__ Uw, float* __restrict__ Ub) {
    int bid = blockIdx.x;
    int tid = threadIdx.x, wid = tid >> 6, lane = tid & 63;
    if (bid < 294) {
        const float* W; _Float16* O; int RW, rt2, half;
        if (bid < 196) { W = gw; O = Gw; RW = KI * 128; rt2 = bid >> 1; half = bid & 1; }
        else { int b2 = bid - 196; W = uw; O = Uw; RW = KI * 64; rt2 = b2 >> 1; half = b2 & 1; }
        int rem0 = rt2 * 256 + lane * 4;
        if (rem0 >= RW) return;
        float w[EDIM][4];
#pragma unroll
        for (int d = 0; d < EDIM; ++d) {
            float4 v = *(const float4*)(W + (long)d * RW + rem0);
            w[d][0] = v.x; w[d][1] = v.y; w[d][2] = v.z; w[d][3] = v.w;
        }
        int n0 = half * 1024 + wid * 256;
        for (int i = 0; i < 256; ++i) {
            int n = n0 + i;
            const float* e = emb + n * EDIM;
            float a0 = 0.f, a1 = 0.f, a2 = 0.f, a3 = 0.f;
#pragma unroll
            for (int d = 0; d < EDIM; ++d) {
                float ed = e[d];
                a0 = fmaf(ed, w[d][0], a0); a1 = fmaf(ed, w[d][1], a1);
                a2 = fmaf(ed, w[d][2], a2); a3 = fmaf(ed, w[d][3], a3);
            }
            us4 pk;
            pk[0] = __builtin_bit_cast(unsigned short, (_Float16)a0);
            pk[1] = __builtin_bit_cast(unsigned short, (_Float16)a1);
            pk[2] = __builtin_bit_cast(unsigned short, (_Float16)a2);
            pk[3] = __builtin_bit_cast(unsigned short, (_Float16)a3);
            *(us4*)(O + (long)n * RW + rem0) = pk;
        }
    } else {
        int bb = bid - 294;
        const int CHUNK = (2048 * 128 + 2048 * 64) / 16;   // 24576
        for (int idx = bb * CHUNK + tid; idx < (bb + 1) * CHUNK; idx += 256) {
            if (idx < 2048 * 128) {
                int n = idx >> 7, o = idx & 127;
                float a = 0.f;
#pragma unroll
                for (int d = 0; d < EDIM; ++d) a = fmaf(emb[n * EDIM + d], gb[d * 128 + o], a);
                Gb[idx] = a;
            } else {
                int i2 = idx - 2048 * 128;
                int n = i2 >> 6, o = i2 & 63;
                float a = 0.f;
#pragma unroll
                for (int d = 0; d < EDIM; ++d) a = fmaf(emb[n * EDIM + d], ub[d * 64 + o], a);
                Ub[i2] = a;
            }
        }
    }
}

// ---------------- build X^T (c,m) f16 for the graph-conv GEMMs ----------------
template <int UPD>
__global__ __launch_bounds__(256) void k_prep(const float* __restrict__ src,
        const float* __restrict__ h, const float* __restrict__ z,
        int t, _Float16* __restrict__ XT) {
    int x = blockIdx.x;   // m-tile (64)
    int y = blockIdx.y;   // 0..15: b, 16: x-cols + pad
    int tid = threadIdx.x;
    if (y < 16) {
        __shared__ float Ls[64][65];
        int b = y, m0 = x * 64;
        int j = tid & 63, rq = tid >> 6;
        for (int rr = 0; rr < 16; ++rr) {
            int rw = rq * 16 + rr;
            long base = ((long)b * N_ + m0 + rw) * DH + j;
            float val = h[base];
            if (UPD) val *= z[base];
            Ls[rw][j] = val;
        }
        __syncthreads();
        int mm = tid & 63, jq = tid >> 6;
        for (int jj = 0; jj < 16; ++jj) {
            int jc = jq * 16 + jj;
            XT[(long)(b * CC + 1 + jc) * N_ + m0 + mm] = (_Float16)Ls[mm][jc];
        }
    } else {
        int m = x * 64 + (tid & 63);
        int cr = tid >> 6;
        for (int cc2 = 0; cc2 < 16; ++cc2) {
            int idx = cr * 16 + cc2;
            long c; float val;
            if (idx < 16) { c = (long)idx * CC; val = src[((long)idx * T_ + t) * N_ + m]; }
            else          { c = NC + (idx - 16); val = 0.f; }
            XT[c * N_ + m] = (_Float16)val;
        }
    }
}

// ---------------- D[n][c] = (1/1024) * sum_m A[n][m] * BT[c][m]; write DT[c][n] f16 ----------------
// global_load_lds w16 staging, XOR-swizzled linear LDS, 2-phase counted-vmcnt pipeline
__device__ __forceinline__ f16x8 lds_frag(const _Float16* base, int r, int kb) {
    int byt = r * 128 + ((kb * 2) ^ ((r & 7) << 4));
    return *(const f16x8*)((const char*)base + byt);
}

__global__ __launch_bounds__(256) void k_gemm(const _Float16* __restrict__ A,
        const _Float16* __restrict__ BT, _Float16* __restrict__ DT) {
    __shared__ __align__(16) _Float16 As[2][64 * 64];
    __shared__ __align__(16) _Float16 Bs[2][64 * 64];
    int bm = blockIdx.x;      // 32 row tiles
    int bc = blockIdx.y;      // 17 col tiles
    int tid = threadIdx.x;
    int wid = tid >> 6, lane = tid & 63;
    int row_g = bm * 64, col_g = bc * 64;
    int r0 = (wid & 1) * 32, c0 = (wid >> 1) * 32;

    // staging constants: instr i covers LDS rows wid*16+i*8 .. +7 (linear dest),
    // source pre-swizzled: lane l loads global k-chunk ((l&7)^(l>>3)) of its row.
    int lr8 = lane >> 3;
    int lsw = 8 * ((lane & 7) ^ lr8);
    long aoff[2], boff[2];
    int ldo[2];
#pragma unroll
    for (int i = 0; i < 2; ++i) {
        aoff[i] = (long)(row_g + wid * 16 + i * 8 + lr8) * N_ + lsw;
        boff[i] = (long)(col_g + wid * 16 + i * 8 + lr8) * N_ + lsw;
        ldo[i] = (wid * 16 + i * 8) * 64;
    }
    auto stage = [&](int buf, int kt) {
        int k0 = kt * 64;
#pragma unroll
        for (int i = 0; i < 2; ++i)
            __builtin_amdgcn_global_load_lds(
                (const __attribute__((address_space(1))) void*)(A + aoff[i] + k0),
                (__attribute__((address_space(3))) void*)&As[buf][ldo[i]], 16, 0, 0);
#pragma unroll
        for (int i = 0; i < 2; ++i)
            __builtin_amdgcn_global_load_lds(
                (const __attribute__((address_space(1))) void*)(BT + boff[i] + k0),
                (__attribute__((address_space(3))) void*)&Bs[buf][ldo[i]], 16, 0, 0);
    };

    f32x4 acc[2][2] = {};
    const int NT = 32;
    stage(0, 0);
    for (int kt = 0; kt < NT; ++kt) {
        int buf = kt & 1;
        if (kt + 1 < NT) {
            stage(buf ^ 1, kt + 1);
            asm volatile("s_waitcnt vmcnt(4)" ::: "memory");
        } else {
            asm volatile("s_waitcnt vmcnt(0)" ::: "memory");
        }
        __builtin_amdgcn_s_barrier();
        const _Float16* Ab = As[buf];
        const _Float16* Bb = Bs[buf];
#pragma unroll
        for (int kk = 0; kk < 64; kk += 32) {
            int kb = kk + (lane >> 4) * 8;
            f16x8 af0 = lds_frag(Ab, r0 + (lane & 15), kb);
            f16x8 af1 = lds_frag(Ab, r0 + 16 + (lane & 15), kb);
            f16x8 bf0 = lds_frag(Bb, c0 + (lane & 15), kb);
            f16x8 bf1 = lds_frag(Bb, c0 + 16 + (lane & 15), kb);
            acc[0][0] = __builtin_amdgcn_mfma_f32_16x16x32_f16(af0, bf0, acc[0][0], 0, 0, 0);
            acc[0][1] = __builtin_amdgcn_mfma_f32_16x16x32_f16(af0, bf1, acc[0][1], 0, 0, 0);
            acc[1][0] = __builtin_amdgcn_mfma_f32_16x16x32_f16(af1, bf0, acc[1][0], 0, 0, 0);
            acc[1][1] = __builtin_amdgcn_mfma_f32_16x16x32_f16(af1, bf1, acc[1][1], 0, 0, 0);
        }
        asm volatile("s_waitcnt lgkmcnt(0)" ::: "memory");
        __builtin_amdgcn_s_barrier();
    }
#pragma unroll
    for (int rt = 0; rt < 2; ++rt)
#pragma unroll
        for (int ct = 0; ct < 2; ++ct) {
            int cg = col_g + c0 + ct * 16 + (lane & 15);
            int ng = row_g + r0 + rt * 16 + ((lane >> 4) << 2);
            us4 pk;
#pragma unroll
            for (int q = 0; q < 4; ++q) pk[q] = __builtin_bit_cast(unsigned short, (_Float16)(acc[rt][ct][q] * AINV));
            *(us4*)(DT + (long)cg * N_ + ng) = pk;
        }
}

// ---------------- gate apply: zr = sigmoid(xg . Gw + Gb) -> z, r ----------------
__global__ __launch_bounds__(256) void k_apply_gate(const float* __restrict__ src,
        const float* __restrict__ h, const _Float16* __restrict__ Y1T,
        const _Float16* __restrict__ Y2T, const _Float16* __restrict__ Gw,
        const float* __restrict__ Gb, int t,
        float* __restrict__ z, float* __restrict__ r) {
    int n = blockIdx.x, tid = threadIdx.x;
    __shared__ float xgf[16 * KI];
    for (int idx = tid; idx < 16 * KI; idx += 256) {
        int b = idx / KI, kk = idx % KI;
        int k = kk / CC, i = kk % CC;
        float ih = (i == 0) ? src[((long)b * T_ + t) * N_ + n]
                            : h[((long)b * N_ + n) * DH + (i - 1)];
        float val;
        if (k == 0)      val = ih;
        else if (k == 1) val = (float)Y1T[(long)(b * CC + i) * N_ + n];
        else             val = 2.f * (float)Y2T[(long)(b * CC + i) * N_ + n] - ih;
        xgf[idx] = val;
    }
    __syncthreads();
    int o = tid & 127, bg = tid >> 7;
    float acc[8];
    float bias = Gb[(long)n * 128 + o];
#pragma unroll
    for (int q = 0; q < 8; ++q) acc[q] = bias;
    const _Float16* W = Gw + (long)n * (KI * 128) + o;
    for (int kk = 0; kk < KI; ++kk) {
        float w = (float)W[(long)kk * 128];
#pragma unroll
        for (int q = 0; q < 8; ++q) acc[q] = fmaf(xgf[(bg * 8 + q) * KI + kk], w, acc[q]);
    }
#pragma unroll
    for (int q = 0; q < 8; ++q) {
        int b = bg * 8 + q;
        float sv = 1.f / (1.f + __expf(-acc[q]));
        long base = ((long)b * N_ + n) * DH;
        if (o < 64) z[base + o] = sv; else r[base + (o - 64)] = sv;
    }
}

// ---------------- update apply: hc = tanh(.); h = r*h + (1-r)*hc; states[t] = h ----------------
__global__ __launch_bounds__(256) void k_apply_update(const float* __restrict__ src,
        float* __restrict__ h, const _Float16* __restrict__ Y1T,
        const _Float16* __restrict__ Y2T, const _Float16* __restrict__ Uw,
        const float* __restrict__ Ub, const float* __restrict__ z,
        const float* __restrict__ rb, int t, _Float16* __restrict__ states) {
    int n = blockIdx.x, tid = threadIdx.x;
    __shared__ float xgf[16 * KI];
    for (int idx = tid; idx < 16 * KI; idx += 256) {
        int b = idx / KI, kk = idx % KI;
        int k = kk / CC, i = kk % CC;
        float ih;
        if (i == 0) ih = src[((long)b * T_ + t) * N_ + n];
        else {
            long base = ((long)b * N_ + n) * DH + (i - 1);
            ih = h[base] * z[base];
        }
        float val;
        if (k == 0)      val = ih;
        else if (k == 1) val = (float)Y1T[(long)(b * CC + i) * N_ + n];
        else             val = 2.f * (float)Y2T[(long)(b * CC + i) * N_ + n] - ih;
        xgf[idx] = val;
    }
    __syncthreads();
    int o = tid & 63, bg = tid >> 6;
    float acc[4];
    float bias = Ub[(long)n * 64 + o];
#pragma unroll
    for (int q = 0; q < 4; ++q) acc[q] = bias;
    const _Float16* W = Uw + (long)n * (KI * 64) + o;
    for (int kk = 0; kk < KI; ++kk) {
        float w = (float)W[(long)kk * 64];
#pragma unroll
        for (int q = 0; q < 4; ++q) acc[q] = fmaf(xgf[(bg * 4 + q) * KI + kk], w, acc[q]);
    }
#pragma unroll
    for (int q = 0; q < 4; ++q) {
        int b = bg * 4 + q;
        long base = ((long)b * N_ + n) * DH + o;
        float hc = tanhf(acc[q]);
        float rv = rb[base], hv = h[base];
        float hn = rv * hv + (1.f - rv) * hc;
        h[base] = hn;
        states[(((long)b * T_ + t) * N_ + n) * DH + o] = (_Float16)hn;
    }
}

// ---------------- fused transformer (only t = T-1 output needed) ----------------
__global__ __launch_bounds__(256) void k_attn(const _Float16* __restrict__ states,
        const float* __restrict__ Wi, const float* __restrict__ bi,
        const float* __restrict__ Wo, const float* __restrict__ bo,
        float* __restrict__ o1) {
    __shared__ _Float16 Wt[64][192];
    __shared__ _Float16 WoT[64][64];
    __shared__ float bis[192], bos[64];
    __shared__ float Xs[4][12][65];
    __shared__ float outs[4][64];
    int tid = threadIdx.x;
    for (int idx = tid; idx < 64 * 192; idx += 256) { int e = idx / 192, j = idx % 192; Wt[e][j] = (_Float16)Wi[j * 64 + e]; }
    for (int idx = tid; idx < 64 * 64; idx += 256) { int e = idx >> 6, j = idx & 63; WoT[e][j] = (_Float16)Wo[j * 64 + e]; }
    for (int idx = tid; idx < 192; idx += 256) bis[idx] = bi[idx];
    for (int idx = tid; idx < 64; idx += 256) bos[idx] = bo[idx];
    __syncthreads();
    int w = tid >> 6, j = tid & 63;
    float divj = __powf(10000.f, -(float)(j & ~1) / 64.f);
    for (int it = 0; it < 8; ++it) {
        int m = blockIdx.x * 4 + w + it * 4096;
        int b = m >> 11, n = m & 2047;
#pragma unroll
        for (int tt = 0; tt < 12; ++tt) {
            float xv = (float)states[(((long)b * T_ + tt) * N_ + n) * DH + j];
            float ang = (float)tt * divj;
            xv += (j & 1) ? __cosf(ang) : __sinf(ang);
            Xs[w][tt][j] = xv;
        }
        __syncthreads();
        float kreg[12], vreg[12];
#pragma unroll
        for (int tt = 0; tt < 12; ++tt) { kreg[tt] = bis[64 + j]; vreg[tt] = bis[128 + j]; }
        float qreg = bis[j];
        for (int e = 0; e < 64; ++e) {
            float wk = (float)Wt[e][64 + j], wv = (float)Wt[e][128 + j];
#pragma unroll
            for (int tt = 0; tt < 12; ++tt) {
                float xv = Xs[w][tt][e];
                kreg[tt] = fmaf(xv, wk, kreg[tt]);
                vreg[tt] = fmaf(xv, wv, vreg[tt]);
            }
            qreg = fmaf(Xs[w][11][e], (float)Wt[e][j], qreg);
        }
        float att[12], mx = -1e30f;
#pragma unroll
        for (int s = 0; s < 12; ++s) {
            float p = qreg * kreg[s];
            p += __shfl_xor(p, 1); p += __shfl_xor(p, 2);
            p += __shfl_xor(p, 4); p += __shfl_xor(p, 8);
            p *= 0.25f;
            att[s] = p; mx = fmaxf(mx, p);
        }
        float se = 0.f;
#pragma unroll
        for (int s = 0; s < 12; ++s) { att[s] = __expf(att[s] - mx); se += att[s]; }
        float inv = 1.f / se, ov = 0.f;
#pragma unroll
        for (int s = 0; s < 12; ++s) ov = fmaf(att[s] * inv, vreg[s], ov);
        outs[w][j] = ov;
        __syncthreads();
        float oo = bos[j];
        for (int e = 0; e < 64; ++e) oo = fmaf(outs[w][e], (float)WoT[e][j], oo);
        o1[(long)m * DH + j] = oo;
        __syncthreads();
    }
}

// ---------------- output head ----------------
__global__ __launch_bounds__(256) void k_final(const float* __restrict__ o1,
        const float* __restrict__ hT, const float* __restrict__ cw,
        const float* __restrict__ convw, const float* __restrict__ convb,
        float* __restrict__ out) {
    __shared__ float Ws[12 * 3 * 64];
    __shared__ float cbs[12];
    int tid = threadIdx.x;
    for (int idx = tid; idx < 12 * 3 * 64; idx += 256) Ws[idx] = convw[idx];
    if (tid < 12) cbs[tid] = convb[tid];
    __syncthreads();
    float c0 = cw[0], c1 = cw[1], c2 = cw[2];
    int g = tid >> 6, j = tid & 63;
    int bn = blockIdx.x * 4 + g;
    int b = bn >> 11, n = bn & 2047;
    float x1 = o1[(long)bn * DH + j];
    float x3 = hT[(long)bn * DH + j];
    float myout = 0.f;
#pragma unroll
    for (int oc = 0; oc < 12; ++oc) {
        float p = x1 * c0 * Ws[(oc * 3 + 0) * 64 + j]
                + x3 * (c1 * Ws[(oc * 3 + 1) * 64 + j] + c2 * Ws[(oc * 3 + 2) * 64 + j]);
        p += __shfl_xor(p, 1); p += __shfl_xor(p, 2); p += __shfl_xor(p, 4);
        p += __shfl_xor(p, 8); p += __shfl_xor(p, 16); p += __shfl_xor(p, 32);
        if (j == oc) myout = p + cbs[oc];
    }
    if (j < 12) out[((long)b * 12 + j) * N_ + n] = myout;
}

extern "C" void kernel_launch(void* const* d_in, const int* in_sizes, int n_in,
                              void* d_out, int out_size, void* d_ws, size_t ws_size,
                              hipStream_t stream) {
    const float* src    = (const float*)d_in[0];
    const float* emb    = (const float*)d_in[2];
    const float* gate_w = (const float*)d_in[3];
    const float* gate_b = (const float*)d_in[4];
    const float* upd_w  = (const float*)d_in[5];
    const float* upd_b  = (const float*)d_in[6];
    const float* a_in_w = (const float*)d_in[7];
    const float* a_in_b = (const float*)d_in[8];
    const float* a_out_w= (const float*)d_in[9];
    const float* a_out_b= (const float*)d_in[10];
    const float* chan_w = (const float*)d_in[11];
    const float* conv_w = (const float*)d_in[12];
    const float* conv_b = (const float*)d_in[13];
    float* out = (float*)d_out;

    char* ws = (char*)d_ws;
    size_t off = 0;
    auto alloc = [&](size_t bytes) { char* p = ws + off; off += (bytes + 255) & ~size_t(255); return p; };
    _Float16* A   = (_Float16*)alloc((size_t)N_ * N_ * 2);
    _Float16* Gw  = (_Float16*)alloc((size_t)N_ * KI * 128 * 2);
    float*  Gb    = (float*) alloc((size_t)N_ * 128 * 4);
    _Float16* Uw  = (_Float16*)alloc((size_t)N_ * KI * 64 * 2);
    float*  Ub    = (float*) alloc((size_t)N_ * 64 * 4);
    _Float16* XT  = (_Float16*)alloc((size_t)NCP * N_ * 2);
    _Float16* Y1T = (_Float16*)alloc((size_t)NCP * N_ * 2);
    _Float16* Y2T = (_Float16*)alloc((size_t)NCP * N_ * 2);
    float*  h    = (float*) alloc((size_t)B_ * N_ * DH * 4);
    float*  zbuf = (float*) alloc((size_t)B_ * N_ * DH * 4);
    float*  rbuf = (float*) alloc((size_t)B_ * N_ * DH * 4);
    _Float16* st = (_Float16*)alloc((size_t)B_ * T_ * N_ * DH * 2);
    float*  o1   = (float*) alloc((size_t)B_ * N_ * DH * 4);
    if (off > ws_size) return;

    hipMemsetAsync(h, 0, (size_t)B_ * N_ * DH * 4, stream);
    k_compA<<<N_, 256, 0, stream>>>(emb, A);
    k_build<<<310, 256, 0, stream>>>(emb, gate_w, gate_b, upd_w, upd_b, Gw, Gb, Uw, Ub);

    dim3 pgrid(32, 17), ggrid(32, 17);
    for (int t = 0; t < T_; ++t) {
        k_prep<0><<<pgrid, 256, 0, stream>>>(src, h, h, t, XT);
        k_gemm<<<ggrid, 256, 0, stream>>>(A, XT, Y1T);
        k_gemm<<<ggrid, 256, 0, stream>>>(A, Y1T, Y2T);
        k_apply_gate<<<N_, 256, 0, stream>>>(src, h, Y1T, Y2T, Gw, Gb, t, zbuf, rbuf);
        k_prep<1><<<pgrid, 256, 0, stream>>>(src, h, zbuf, t, XT);
        k_gemm<<<ggrid, 256, 0, stream>>>(A, XT, Y1T);
        k_gemm<<<ggrid, 256, 0, stream>>>(A, Y1T, Y2T);
        k_apply_update<<<N_, 256, 0, stream>>>(src, h, Y1T, Y2T, Uw, Ub, zbuf, rbuf, t, st);
    }
    k_attn<<<1024, 256, 0, stream>>>(st, a_in_w, a_in_b, a_out_w, a_out_b, o1);
    k_final<<<8192, 256, 0, stream>>>(o1, h, chan_w, conv_w, conv_b, out);
}

// Round 4
// 2938.310 us; speedup vs baseline: 1.2110x; 1.0744x over previous
//
#include <hip/hip_runtime.h>
#include <hip/hip_bf16.h>

typedef _Float16 f16x8 __attribute__((ext_vector_type(8)));
typedef _Float16 f16x4 __attribute__((ext_vector_type(4)));
typedef float f32x4 __attribute__((ext_vector_type(4)));
typedef unsigned short us8 __attribute__((ext_vector_type(8)));
typedef unsigned short us4 __attribute__((ext_vector_type(4)));

#define N_ 2048
#define B_ 16
#define T_ 12
#define DH 64
#define CC 65      // DIN + DOUT
#define NC 1040    // B_*CC
#define NCP 1088   // padded col count (17*64)
#define KI 195     // K*CC
#define EDIM 10
#define ASCALE 1024.0f
#define AINV (1.0f / 1024.0f)

// ---------------- A = softmax(relu(E E^T)) rowwise, f16 scaled by 1024 ----------------
__global__ __launch_bounds__(256) void k_compA(const float* __restrict__ emb,
                                               _Float16* __restrict__ A) {
    int n = blockIdx.x, tid = threadIdx.x;
    float en[EDIM];
#pragma unroll
    for (int d = 0; d < EDIM; ++d) en[d] = emb[n * EDIM + d];
    float v[8], mx = -1e30f;
#pragma unroll
    for (int j = 0; j < 8; ++j) {
        int m = tid + j * 256;
        float acc = 0.f;
#pragma unroll
        for (int d = 0; d < EDIM; ++d) acc = fmaf(en[d], emb[m * EDIM + d], acc);
        acc = fmaxf(acc, 0.f);
        v[j] = acc; mx = fmaxf(mx, acc);
    }
    __shared__ float red[256];
    red[tid] = mx; __syncthreads();
    for (int s = 128; s > 0; s >>= 1) { if (tid < s) red[tid] = fmaxf(red[tid], red[tid + s]); __syncthreads(); }
    mx = red[0]; __syncthreads();
    float se = 0.f;
#pragma unroll
    for (int j = 0; j < 8; ++j) { v[j] = __expf(v[j] - mx); se += v[j]; }
    red[tid] = se; __syncthreads();
    for (int s = 128; s > 0; s >>= 1) { if (tid < s) red[tid] += red[tid + s]; __syncthreads(); }
    float inv = ASCALE / red[0];
#pragma unroll
    for (int j = 0; j < 8; ++j) A[(long)n * N_ + tid + j * 256] = (_Float16)(v[j] * inv);
}

// ---------------- per-node GRU weights (f16) + biases (f32), outer-product, 8x n-split ----------------
__global__ __launch_bounds__(256) void k_build(const float* __restrict__ emb,
        const float* __restrict__ gw, const float* __restrict__ gb,
        const float* __restrict__ uw, const float* __restrict__ ub,
        _Float16* __restrict__ Gw, float* __restrict__ Gb,
        _Float16* __restrict__ Uw, float* __restrict__ Ub) {
    int bid = blockIdx.x;
    int tid = threadIdx.x, wid = tid >> 6, lane = tid & 63;
    if (bid < 1176) {
        int slice = bid >> 3, chunk = bid & 7;
        const float* W; _Float16* O; int RW;
        int rt2;
        if (slice < 98) { W = gw; O = Gw; RW = KI * 128; rt2 = slice; }
        else { W = uw; O = Uw; RW = KI * 64; rt2 = slice - 98; }
        int rem0 = rt2 * 256 + lane * 4;
        if (rem0 >= RW) return;
        float w[EDIM][4];
#pragma unroll
        for (int d = 0; d < EDIM; ++d) {
            float4 v = *(const float4*)(W + (long)d * RW + rem0);
            w[d][0] = v.x; w[d][1] = v.y; w[d][2] = v.z; w[d][3] = v.w;
        }
        int n0 = chunk * 256 + wid * 64;
        for (int i = 0; i < 64; ++i) {
            int n = n0 + i;
            const float* e = emb + n * EDIM;
            float a0 = 0.f, a1 = 0.f, a2 = 0.f, a3 = 0.f;
#pragma unroll
            for (int d = 0; d < EDIM; ++d) {
                float ed = e[d];
                a0 = fmaf(ed, w[d][0], a0); a1 = fmaf(ed, w[d][1], a1);
                a2 = fmaf(ed, w[d][2], a2); a3 = fmaf(ed, w[d][3], a3);
            }
            us4 pk;
            pk[0] = __builtin_bit_cast(unsigned short, (_Float16)a0);
            pk[1] = __builtin_bit_cast(unsigned short, (_Float16)a1);
            pk[2] = __builtin_bit_cast(unsigned short, (_Float16)a2);
            pk[3] = __builtin_bit_cast(unsigned short, (_Float16)a3);
            *(us4*)(O + (long)n * RW + rem0) = pk;
        }
    } else {
        int bb = bid - 1176;
        const int CHUNK = (2048 * 128 + 2048 * 64) / 16;   // 24576
        for (int idx = bb * CHUNK + tid; idx < (bb + 1) * CHUNK; idx += 256) {
            if (idx < 2048 * 128) {
                int n = idx >> 7, o = idx & 127;
                float a = 0.f;
#pragma unroll
                for (int d = 0; d < EDIM; ++d) a = fmaf(emb[n * EDIM + d], gb[d * 128 + o], a);
                Gb[idx] = a;
            } else {
                int i2 = idx - 2048 * 128;
                int n = i2 >> 6, o = i2 & 63;
                float a = 0.f;
#pragma unroll
                for (int d = 0; d < EDIM; ++d) a = fmaf(emb[n * EDIM + d], ub[d * 64 + o], a);
                Ub[i2] = a;
            }
        }
    }
}

// ---------------- tiny: f16 copies of attn weights ----------------
__global__ __launch_bounds__(256) void k_wcvt(const float* __restrict__ Wi,
        const float* __restrict__ Wo, _Float16* __restrict__ Wi16,
        _Float16* __restrict__ Wo16) {
    int idx = blockIdx.x * 256 + threadIdx.x;
    if (idx < 192 * 64) Wi16[idx] = (_Float16)Wi[idx];
    if (idx < 64 * 64) Wo16[idx] = (_Float16)Wo[idx];
}

// ---------------- tiny: XT x-row for t=0 (pad+h rows zeroed by memset) ----------------
__global__ __launch_bounds__(256) void k_initx(const float* __restrict__ src,
        _Float16* __restrict__ XT) {
    int idx = blockIdx.x * 256 + threadIdx.x;   // b*2048+n
    int b = idx >> 11, n = idx & 2047;
    XT[((long)b * CC) * N_ + n] = (_Float16)src[((long)b * T_) * N_ + n];
}

// ---------------- D[n][c] = (1/1024) * sum_m A[n][m] * BT[c][m]; write DT[c][n] f16 ----------------
__device__ __forceinline__ f16x8 lds_frag(const _Float16* base, int r, int kb) {
    int byt = r * 128 + ((kb * 2) ^ ((r & 7) << 4));
    return *(const f16x8*)((const char*)base + byt);
}

__global__ __launch_bounds__(256) void k_gemm(const _Float16* __restrict__ A,
        const _Float16* __restrict__ BT, _Float16* __restrict__ DT) {
    __shared__ __align__(16) _Float16 As[2][64 * 64];
    __shared__ __align__(16) _Float16 Bs[2][64 * 64];
    int bm = blockIdx.x;
    int bc = blockIdx.y;
    int tid = threadIdx.x;
    int wid = tid >> 6, lane = tid & 63;
    int row_g = bm * 64, col_g = bc * 64;
    int r0 = (wid & 1) * 32, c0 = (wid >> 1) * 32;

    int lr8 = lane >> 3;
    int lsw = 8 * ((lane & 7) ^ lr8);
    long aoff[2], boff[2];
    int ldo[2];
#pragma unroll
    for (int i = 0; i < 2; ++i) {
        aoff[i] = (long)(row_g + wid * 16 + i * 8 + lr8) * N_ + lsw;
        boff[i] = (long)(col_g + wid * 16 + i * 8 + lr8) * N_ + lsw;
        ldo[i] = (wid * 16 + i * 8) * 64;
    }
    auto stage = [&](int buf, int kt) {
        int k0 = kt * 64;
#pragma unroll
        for (int i = 0; i < 2; ++i)
            __builtin_amdgcn_global_load_lds(
                (const __attribute__((address_space(1))) void*)(A + aoff[i] + k0),
                (__attribute__((address_space(3))) void*)&As[buf][ldo[i]], 16, 0, 0);
#pragma unroll
        for (int i = 0; i < 2; ++i)
            __builtin_amdgcn_global_load_lds(
                (const __attribute__((address_space(1))) void*)(BT + boff[i] + k0),
                (__attribute__((address_space(3))) void*)&Bs[buf][ldo[i]], 16, 0, 0);
    };

    f32x4 acc[2][2] = {};
    const int NT = 32;
    stage(0, 0);
    for (int kt = 0; kt < NT; ++kt) {
        int buf = kt & 1;
        if (kt + 1 < NT) {
            stage(buf ^ 1, kt + 1);
            asm volatile("s_waitcnt vmcnt(4)" ::: "memory");
        } else {
            asm volatile("s_waitcnt vmcnt(0)" ::: "memory");
        }
        __builtin_amdgcn_s_barrier();
        const _Float16* Ab = As[buf];
        const _Float16* Bb = Bs[buf];
#pragma unroll
        for (int kk = 0; kk < 64; kk += 32) {
            int kb = kk + (lane >> 4) * 8;
            f16x8 af0 = lds_frag(Ab, r0 + (lane & 15), kb);
            f16x8 af1 = lds_frag(Ab, r0 + 16 + (lane & 15), kb);
            f16x8 bf0 = lds_frag(Bb, c0 + (lane & 15), kb);
            f16x8 bf1 = lds_frag(Bb, c0 + 16 + (lane & 15), kb);
            acc[0][0] = __builtin_amdgcn_mfma_f32_16x16x32_f16(af0, bf0, acc[0][0], 0, 0, 0);
            acc[0][1] = __builtin_amdgcn_mfma_f32_16x16x32_f16(af0, bf1, acc[0][1], 0, 0, 0);
            acc[1][0] = __builtin_amdgcn_mfma_f32_16x16x32_f16(af1, bf0, acc[1][0], 0, 0, 0);
            acc[1][1] = __builtin_amdgcn_mfma_f32_16x16x32_f16(af1, bf1, acc[1][1], 0, 0, 0);
        }
        asm volatile("s_waitcnt lgkmcnt(0)" ::: "memory");
        __builtin_amdgcn_s_barrier();
    }
#pragma unroll
    for (int rt = 0; rt < 2; ++rt)
#pragma unroll
        for (int ct = 0; ct < 2; ++ct) {
            int cg = col_g + c0 + ct * 16 + (lane & 15);
            int ng = row_g + r0 + rt * 16 + ((lane >> 4) << 2);
            us4 pk;
#pragma unroll
            for (int q = 0; q < 4; ++q) pk[q] = __builtin_bit_cast(unsigned short, (_Float16)(acc[rt][ct][q] * AINV));
            *(us4*)(DT + (long)cg * N_ + ng) = pk;
        }
}

// ---------------- gate apply: zr = sigmoid(xg . Gw + Gb) -> z, r; XT h-rows <- z*h ----------------
__global__ __launch_bounds__(256) void k_apply_gate(const float* __restrict__ src,
        const float* __restrict__ h, const _Float16* __restrict__ Y1T,
        const _Float16* __restrict__ Y2T, const _Float16* __restrict__ Gw,
        const float* __restrict__ Gb, int t,
        float* __restrict__ z, float* __restrict__ r, _Float16* __restrict__ XT) {
    int n = blockIdx.x, tid = threadIdx.x;
    __shared__ float xgf[16 * KI];
    for (int idx = tid; idx < 16 * KI; idx += 256) {
        int b = idx / KI, kk = idx % KI;
        int k = kk / CC, i = kk % CC;
        float ih = (i == 0) ? src[((long)b * T_ + t) * N_ + n]
                            : h[((long)b * N_ + n) * DH + (i - 1)];
        float val;
        if (k == 0)      val = ih;
        else if (k == 1) val = (float)Y1T[(long)(b * CC + i) * N_ + n];
        else             val = 2.f * (float)Y2T[(long)(b * CC + i) * N_ + n] - ih;
        xgf[idx] = val;
    }
    __syncthreads();
    int o = tid & 127, bg = tid >> 7;
    float acc[8];
    float bias = Gb[(long)n * 128 + o];
#pragma unroll
    for (int q = 0; q < 8; ++q) acc[q] = bias;
    const _Float16* W = Gw + (long)n * (KI * 128) + o;
    for (int kk = 0; kk < KI; ++kk) {
        float w = (float)W[(long)kk * 128];
#pragma unroll
        for (int q = 0; q < 8; ++q) acc[q] = fmaf(xgf[(bg * 8 + q) * KI + kk], w, acc[q]);
    }
#pragma unroll
    for (int q = 0; q < 8; ++q) {
        int b = bg * 8 + q;
        float sv = 1.f / (1.f + __expf(-acc[q]));
        long base = ((long)b * N_ + n) * DH;
        if (o < 64) {
            z[base + o] = sv;
            XT[(long)(b * CC + 1 + o) * N_ + n] = (_Float16)(sv * h[base + o]);
        } else {
            r[base + (o - 64)] = sv;
        }
    }
}

// ---------------- update apply: hc=tanh(.); h=r*h+(1-r)*hc; states[t]=h; XT rows for t+1 ----------------
__global__ __launch_bounds__(256) void k_apply_update(const float* __restrict__ src,
        float* __restrict__ h, const _Float16* __restrict__ Y1T,
        const _Float16* __restrict__ Y2T, const _Float16* __restrict__ Uw,
        const float* __restrict__ Ub, const float* __restrict__ z,
        const float* __restrict__ rb, int t, _Float16* __restrict__ states,
        _Float16* __restrict__ XT) {
    int n = blockIdx.x, tid = threadIdx.x;
    __shared__ float xgf[16 * KI];
    for (int idx = tid; idx < 16 * KI; idx += 256) {
        int b = idx / KI, kk = idx % KI;
        int k = kk / CC, i = kk % CC;
        float ih;
        if (i == 0) ih = src[((long)b * T_ + t) * N_ + n];
        else {
            long base = ((long)b * N_ + n) * DH + (i - 1);
            ih = h[base] * z[base];
        }
        float val;
        if (k == 0)      val = ih;
        else if (k == 1) val = (float)Y1T[(long)(b * CC + i) * N_ + n];
        else             val = 2.f * (float)Y2T[(long)(b * CC + i) * N_ + n] - ih;
        xgf[idx] = val;
    }
    __syncthreads();
    int o = tid & 63, bg = tid >> 6;
    float acc[4];
    float bias = Ub[(long)n * 64 + o];
#pragma unroll
    for (int q = 0; q < 4; ++q) acc[q] = bias;
    const _Float16* W = Uw + (long)n * (KI * 64) + o;
    for (int kk = 0; kk < KI; ++kk) {
        float w = (float)W[(long)kk * 64];
#pragma unroll
        for (int q = 0; q < 4; ++q) acc[q] = fmaf(xgf[(bg * 4 + q) * KI + kk], w, acc[q]);
    }
#pragma unroll
    for (int q = 0; q < 4; ++q) {
        int b = bg * 4 + q;
        long base = ((long)b * N_ + n) * DH + o;
        float hc = tanhf(acc[q]);
        float rv = rb[base], hv = h[base];
        float hn = rv * hv + (1.f - rv) * hc;
        h[base] = hn;
        states[(((long)b * T_ + t) * N_ + n) * DH + o] = (_Float16)hn;
        XT[(long)(b * CC + 1 + o) * N_ + n] = (_Float16)hn;
        if (o == 0 && t + 1 < T_)
            XT[(long)(b * CC) * N_ + n] = (_Float16)src[((long)b * T_ + t + 1) * N_ + n];
    }
}

// ---------------- qkv projection (MFMA): KV for all t, Q at t=11 ----------------
__global__ __launch_bounds__(256) void k_qkv(const _Float16* __restrict__ st,
        const _Float16* __restrict__ Wi16, const float* __restrict__ bi,
        _Float16* __restrict__ KV, _Float16* __restrict__ Q) {
    int bt = blockIdx.x;        // b*12 + t
    int nck = blockIdx.y;       // n-chunk of 128
    int b = bt / 12, t = bt % 12;
    int tid = threadIdx.x, wid = tid >> 6, lane = tid & 63;
    __shared__ float pe[64];
    __shared__ __align__(16) _Float16 Xs[128][72];
    if (tid < 64) {
        int e = tid;
        float div = __powf(10000.f, -(float)(e & ~1) / 64.f);
        float ang = (float)t * div;
        pe[e] = (e & 1) ? __cosf(ang) : __sinf(ang);
    }
    __syncthreads();
    const _Float16* srcp = st + ((long)(b * T_ + t) * N_ + nck * 128) * DH;
#pragma unroll
    for (int u = 0; u < 4; ++u) {
        int idx = u * 256 + tid;
        int rr = idx >> 3, e0 = (idx & 7) * 8;
        f16x8 v = *(const f16x8*)(srcp + rr * DH + e0);
        f16x8 ov;
#pragma unroll
        for (int q = 0; q < 8; ++q) ov[q] = (_Float16)((float)v[q] + pe[e0 + q]);
        *(f16x8*)&Xs[rr][e0] = ov;
    }
    __syncthreads();
    int cl = lane & 15, ks8 = (lane >> 4) * 8;
    f16x8 bfrag[3][2];
    float bias[3];
#pragma unroll
    for (int j = 0; j < 3; ++j) {
        int c = (wid * 3 + j) * 16 + cl;
#pragma unroll
        for (int ks = 0; ks < 2; ++ks)
            bfrag[j][ks] = *(const f16x8*)(Wi16 + c * 64 + ks * 32 + ks8);
        bias[j] = bi[c];
    }
    f32x4 acc[8][3] = {};
#pragma unroll
    for (int rt = 0; rt < 8; ++rt) {
#pragma unroll
        for (int ks = 0; ks < 2; ++ks) {
            f16x8 af = *(const f16x8*)&Xs[rt * 16 + cl][ks * 32 + ks8];
#pragma unroll
            for (int j = 0; j < 3; ++j)
                acc[rt][j] = __builtin_amdgcn_mfma_f32_16x16x32_f16(af, bfrag[j][ks], acc[rt][j], 0, 0, 0);
        }
    }
    int rowq = (lane >> 4) * 4;
#pragma unroll
    for (int rt = 0; rt < 8; ++rt)
#pragma unroll
        for (int j = 0; j < 3; ++j) {
            int c = (wid * 3 + j) * 16 + cl;
#pragma unroll
            for (int q = 0; q < 4; ++q) {
                int n = nck * 128 + rt * 16 + rowq + q;
                float val = acc[rt][j][q] + bias[j];
                if (c >= 64)
                    KV[(((long)b * N_ + n) * T_ + t) * 128 + (c - 64)] = (_Float16)val;
                else if (t == 11)
                    Q[((long)b * N_ + n) * 64 + c] = (_Float16)val;
            }
        }
}

// ---------------- attention + out-proj: 16 pairs/block, 16 threads/pair ----------------
__global__ __launch_bounds__(256) void k_attn2(const _Float16* __restrict__ KV,
        const _Float16* __restrict__ Q, const _Float16* __restrict__ Wo16,
        const float* __restrict__ bo, float* __restrict__ o1) {
    __shared__ _Float16 kvs[16 * 1544];     // 12*128 + 8 pad per pair
    __shared__ float qs[16][64];
    __shared__ float Wos[64][64];           // [c][j]
    __shared__ float outb[16][64];
    __shared__ float bos[64];
    int tid = threadIdx.x;
    long pair0 = (long)blockIdx.x * 16;
#pragma unroll
    for (int u = 0; u < 12; ++u) {
        int idx = u * 256 + tid;
        int p = idx / 192, off8 = (idx % 192) * 8;
        *(f16x8*)&kvs[p * 1544 + off8] = *(const f16x8*)(KV + (pair0 + p) * 1536 + off8);
    }
    if (tid < 64) bos[tid] = bo[tid];
    for (int idx = tid; idx < 1024; idx += 256) {
        int p = idx >> 6, j = idx & 63;
        qs[p][j] = (float)Q[(pair0 + p) * 64 + j];
    }
    for (int idx = tid; idx < 4096; idx += 256) {
        int c = idx >> 6, j = idx & 63;
        Wos[c][j] = (float)Wo16[j * 64 + c];
    }
    __syncthreads();
    int p = tid >> 4, i = tid & 15;
    int h = i >> 2, sg = i & 3;
    const _Float16* kvp = &kvs[p * 1544];
    float att3[3], mx = -1e30f;
#pragma unroll
    for (int j = 0; j < 3; ++j) {
        int s = sg + 4 * j;
        float sc = 0.f;
#pragma unroll
        for (int d = 0; d < 16; ++d)
            sc = fmaf(qs[p][h * 16 + d], (float)kvp[s * 128 + h * 16 + d], sc);
        att3[j] = sc * 0.25f;
        mx = fmaxf(mx, att3[j]);
    }
    mx = fmaxf(mx, __shfl_xor(mx, 1));
    mx = fmaxf(mx, __shfl_xor(mx, 2));
    float se = 0.f;
#pragma unroll
    for (int j = 0; j < 3; ++j) { att3[j] = __expf(att3[j] - mx); se += att3[j]; }
    se += __shfl_xor(se, 1);
    se += __shfl_xor(se, 2);
    float inv = 1.f / se;
#pragma unroll
    for (int j = 0; j < 3; ++j) att3[j] *= inv;
    int c0 = i * 4;
    float out4[4] = {0.f, 0.f, 0.f, 0.f};
#pragma unroll
    for (int m = 0; m < 4; ++m) {
        float a0 = __shfl_xor(att3[0], m);
        float a1 = __shfl_xor(att3[1], m);
        float a2 = __shfl_xor(att3[2], m);
        int sb = sg ^ m;
        float aj[3] = {a0, a1, a2};
#pragma unroll
        for (int j = 0; j < 3; ++j) {
            int s = sb + 4 * j;
            f16x4 vv = *(const f16x4*)&kvp[s * 128 + 64 + c0];
#pragma unroll
            for (int q = 0; q < 4; ++q) out4[q] = fmaf(aj[j], (float)vv[q], out4[q]);
        }
    }
    *(float4*)&outb[p][c0] = *(float4*)out4;
    __syncthreads();
    float res[4];
#pragma unroll
    for (int q = 0; q < 4; ++q) res[q] = bos[c0 + q];
    for (int c = 0; c < 64; ++c) {
        float oc = outb[p][c];
        float4 wv = *(const float4*)&Wos[c][c0];
        res[0] = fmaf(oc, wv.x, res[0]);
        res[1] = fmaf(oc, wv.y, res[1]);
        res[2] = fmaf(oc, wv.z, res[2]);
        res[3] = fmaf(oc, wv.w, res[3]);
    }
    *(float4*)&o1[(pair0 + p) * 64 + c0] = make_float4(res[0], res[1], res[2], res[3]);
}

// ---------------- output head ----------------
__global__ __launch_bounds__(256) void k_final(const float* __restrict__ o1,
        const float* __restrict__ hT, const float* __restrict__ cw,
        const float* __restrict__ convw, const float* __restrict__ convb,
        float* __restrict__ out) {
    __shared__ float Ws[12 * 3 * 64];
    __shared__ float cbs[12];
    int tid = threadIdx.x;
    for (int idx = tid; idx < 12 * 3 * 64; idx += 256) Ws[idx] = convw[idx];
    if (tid < 12) cbs[tid] = convb[tid];
    __syncthreads();
    float c0 = cw[0], c1 = cw[1], c2 = cw[2];
    int g = tid >> 6, j = tid & 63;
    int bn = blockIdx.x * 4 + g;
    int b = bn >> 11, n = bn & 2047;
    float x1 = o1[(long)bn * DH + j];
    float x3 = hT[(long)bn * DH + j];
    float myout = 0.f;
#pragma unroll
    for (int oc = 0; oc < 12; ++oc) {
        float p = x1 * c0 * Ws[(oc * 3 + 0) * 64 + j]
                + x3 * (c1 * Ws[(oc * 3 + 1) * 64 + j] + c2 * Ws[(oc * 3 + 2) * 64 + j]);
        p += __shfl_xor(p, 1); p += __shfl_xor(p, 2); p += __shfl_xor(p, 4);
        p += __shfl_xor(p, 8); p += __shfl_xor(p, 16); p += __shfl_xor(p, 32);
        if (j == oc) myout = p + cbs[oc];
    }
    if (j < 12) out[((long)b * 12 + j) * N_ + n] = myout;
}

extern "C" void kernel_launch(void* const* d_in, const int* in_sizes, int n_in,
                              void* d_out, int out_size, void* d_ws, size_t ws_size,
                              hipStream_t stream) {
    const float* src    = (const float*)d_in[0];
    const float* emb    = (const float*)d_in[2];
    const float* gate_w = (const float*)d_in[3];
    const float* gate_b = (const float*)d_in[4];
    const float* upd_w  = (const float*)d_in[5];
    const float* upd_b  = (const float*)d_in[6];
    const float* a_in_w = (const float*)d_in[7];
    const float* a_in_b = (const float*)d_in[8];
    const float* a_out_w= (const float*)d_in[9];
    const float* a_out_b= (const float*)d_in[10];
    const float* chan_w = (const float*)d_in[11];
    const float* conv_w = (const float*)d_in[12];
    const float* conv_b = (const float*)d_in[13];
    float* out = (float*)d_out;

    char* ws = (char*)d_ws;
    size_t off = 0;
    auto alloc = [&](size_t bytes) { char* p = ws + off; off += (bytes + 255) & ~size_t(255); return p; };
    _Float16* A   = (_Float16*)alloc((size_t)N_ * N_ * 2);
    _Float16* Gw  = (_Float16*)alloc((size_t)N_ * KI * 128 * 2);
    float*  Gb    = (float*) alloc((size_t)N_ * 128 * 4);
    _Float16* Uw  = (_Float16*)alloc((size_t)N_ * KI * 64 * 2);
    float*  Ub    = (float*) alloc((size_t)N_ * 64 * 4);
    _Float16* XT  = (_Float16*)alloc((size_t)NCP * N_ * 2);
    _Float16* Y1T = (_Float16*)alloc((size_t)NCP * N_ * 2);
    _Float16* Y2T = (_Float16*)alloc((size_t)NCP * N_ * 2);
    float*  h    = (float*) alloc((size_t)B_ * N_ * DH * 4);
    float*  zbuf = (float*) alloc((size_t)B_ * N_ * DH * 4);
    float*  rbuf = (float*) alloc((size_t)B_ * N_ * DH * 4);
    _Float16* stt = (_Float16*)alloc((size_t)B_ * T_ * N_ * DH * 2);
    _Float16* Wi16 = (_Float16*)alloc(192 * 64 * 2);
    _Float16* Wo16 = (_Float16*)alloc(64 * 64 * 2);
    if (off > ws_size) return;

    // dead-region aliases for post-GRU phase
    _Float16* KV = Gw;          // 100.7 MB into Gw's 102.2 MB
    _Float16* Qb = Uw;          // 4.2 MB into Uw's 51.1 MB
    float*    o1 = zbuf;        // 8.4 MB, zbuf dead after loop

    hipMemsetAsync(h, 0, (size_t)B_ * N_ * DH * 4, stream);
    hipMemsetAsync(XT, 0, (size_t)NCP * N_ * 2, stream);
    k_compA<<<N_, 256, 0, stream>>>(emb, A);
    k_build<<<1192, 256, 0, stream>>>(emb, gate_w, gate_b, upd_w, upd_b, Gw, Gb, Uw, Ub);
    k_wcvt<<<48, 256, 0, stream>>>(a_in_w, a_out_w, Wi16, Wo16);
    k_initx<<<128, 256, 0, stream>>>(src, XT);

    dim3 ggrid(32, 17);
    for (int t = 0; t < T_; ++t) {
        k_gemm<<<ggrid, 256, 0, stream>>>(A, XT, Y1T);
        k_gemm<<<ggrid, 256, 0, stream>>>(A, Y1T, Y2T);
        k_apply_gate<<<N_, 256, 0, stream>>>(src, h, Y1T, Y2T, Gw, Gb, t, zbuf, rbuf, XT);
        k_gemm<<<ggrid, 256, 0, stream>>>(A, XT, Y1T);
        k_gemm<<<ggrid, 256, 0, stream>>>(A, Y1T, Y2T);
        k_apply_update<<<N_, 256, 0, stream>>>(src, h, Y1T, Y2T, Uw, Ub, zbuf, rbuf, t, stt, XT);
    }
    dim3 qgrid(192, 16);
    k_qkv<<<qgrid, 256, 0, stream>>>(stt, Wi16, a_in_b, KV, Qb);
    k_attn2<<<2048, 256, 0, stream>>>(KV, Qb, Wo16, a_out_b, o1);
    k_final<<<8192, 256, 0, stream>>>(o1, h, chan_w, conv_w, conv_b, out);
}

// Round 7
// 2659.934 us; speedup vs baseline: 1.3377x; 1.1047x over previous
//
#include <hip/hip_runtime.h>
#include <hip/hip_bf16.h>

typedef _Float16 f16x8 __attribute__((ext_vector_type(8)));
typedef _Float16 f16x4 __attribute__((ext_vector_type(4)));
typedef float f32x4 __attribute__((ext_vector_type(4)));
typedef unsigned short us8 __attribute__((ext_vector_type(8)));
typedef unsigned short us4 __attribute__((ext_vector_type(4)));

#define N_ 2048
#define B_ 16
#define T_ 12
#define DH 64
#define CC 65      // DIN + DOUT
#define NC 1040    // B_*CC
#define NCP 1088   // padded col count (17*64)
#define KI 195     // K*CC
#define KP 200     // row stride (16B-aligned); MFMA reads to 224 w/ zero-A overlap
#define EDIM 10
#define ASCALE 1024.0f
#define AINV (1.0f / 1024.0f)

// ---------------- A = softmax(relu(E E^T)) rowwise, f16 scaled by 1024 ----------------
__global__ __launch_bounds__(256) void k_compA(const float* __restrict__ emb,
                                               _Float16* __restrict__ A) {
    int n = blockIdx.x, tid = threadIdx.x;
    float en[EDIM];
#pragma unroll
    for (int d = 0; d < EDIM; ++d) en[d] = emb[n * EDIM + d];
    float v[8], mx = -1e30f;
#pragma unroll
    for (int j = 0; j < 8; ++j) {
        int m = tid + j * 256;
        float acc = 0.f;
#pragma unroll
        for (int d = 0; d < EDIM; ++d) acc = fmaf(en[d], emb[m * EDIM + d], acc);
        acc = fmaxf(acc, 0.f);
        v[j] = acc; mx = fmaxf(mx, acc);
    }
    __shared__ float red[256];
    red[tid] = mx; __syncthreads();
    for (int s = 128; s > 0; s >>= 1) { if (tid < s) red[tid] = fmaxf(red[tid], red[tid + s]); __syncthreads(); }
    mx = red[0]; __syncthreads();
    float se = 0.f;
#pragma unroll
    for (int j = 0; j < 8; ++j) { v[j] = __expf(v[j] - mx); se += v[j]; }
    red[tid] = se; __syncthreads();
    for (int s = 128; s > 0; s >>= 1) { if (tid < s) red[tid] += red[tid + s]; __syncthreads(); }
    float inv = ASCALE / red[0];
#pragma unroll
    for (int j = 0; j < 8; ++j) A[(long)n * N_ + tid + j * 256] = (_Float16)(v[j] * inv);
}

// ---------------- per-node GRU weights TRANSPOSED: GwT[n][o][kk], stride KP=200 ----------------
__global__ __launch_bounds__(256) void k_build(const float* __restrict__ emb,
        const float* __restrict__ gw, const float* __restrict__ gb,
        const float* __restrict__ uw, const float* __restrict__ ub,
        _Float16* __restrict__ GwT, float* __restrict__ Gb,
        _Float16* __restrict__ UwT, float* __restrict__ Ub) {
    int bid = blockIdx.x;
    int tid = threadIdx.x;
    if (bid < 1536) {
        int oc = bid >> 3, nblk = bid & 7;
        const float* W; _Float16* O; int no, o;
        if (oc < 128) { W = gw; O = GwT; no = 128; o = oc; }
        else { W = uw; O = UwT; no = 64; o = oc - 128; }
        long RW = (long)KI * no;
        __shared__ float gcol[EDIM][196];
        __shared__ float embs[256][EDIM];
        for (int idx = tid; idx < EDIM * KI; idx += 256) {
            int d = idx / KI, kk = idx % KI;
            gcol[d][kk] = W[d * RW + (long)kk * no + o];
        }
        for (int idx = tid; idx < 256 * EDIM; idx += 256)
            embs[idx / EDIM][idx % EDIM] = emb[(nblk * 256 + idx / EDIM) * EDIM + idx % EDIM];
        __syncthreads();
        if (tid < 200) {
            int n_sub = tid / 25, kkc = tid % 25;
            int kk0 = kkc * 8;
            for (int i = 0; i < 32; ++i) {
                int nl = n_sub * 32 + i;
                int n = nblk * 256 + nl;
                float e[EDIM];
#pragma unroll
                for (int d = 0; d < EDIM; ++d) e[d] = embs[nl][d];
                us8 pk;
#pragma unroll
                for (int j = 0; j < 8; ++j) {
                    int kk = kk0 + j;
                    float a = 0.f;
                    if (kk < KI) {
#pragma unroll
                        for (int d = 0; d < EDIM; ++d) a = fmaf(e[d], gcol[d][kk], a);
                    }
                    pk[j] = __builtin_bit_cast(unsigned short, (_Float16)a);
                }
                *(us8*)(O + (long)n * no * KP + o * KP + kk0) = pk;
            }
        }
    } else {
        int bb = bid - 1536;
        const int CHUNK = (2048 * 128 + 2048 * 64) / 16;   // 24576
        for (int idx = bb * CHUNK + tid; idx < (bb + 1) * CHUNK; idx += 256) {
            if (idx < 2048 * 128) {
                int n = idx >> 7, o = idx & 127;
                float a = 0.f;
#pragma unroll
                for (int d = 0; d < EDIM; ++d) a = fmaf(emb[n * EDIM + d], gb[d * 128 + o], a);
                Gb[idx] = a;
            } else {
                int i2 = idx - 2048 * 128;
                int n = i2 >> 6, o = i2 & 63;
                float a = 0.f;
#pragma unroll
                for (int d = 0; d < EDIM; ++d) a = fmaf(emb[n * EDIM + d], ub[d * 64 + o], a);
                Ub[i2] = a;
            }
        }
    }
}

// ---------------- tiny: f16 copies of attn weights ----------------
__global__ __launch_bounds__(256) void k_wcvt(const float* __restrict__ Wi,
        const float* __restrict__ Wo, _Float16* __restrict__ Wi16,
        _Float16* __restrict__ Wo16) {
    int idx = blockIdx.x * 256 + threadIdx.x;
    if (idx < 192 * 64) Wi16[idx] = (_Float16)Wi[idx];
    if (idx < 64 * 64) Wo16[idx] = (_Float16)Wo[idx];
}

// ---------------- tiny: XT x-row for t=0 (pad+h rows zeroed by memset) ----------------
__global__ __launch_bounds__(256) void k_initx(const float* __restrict__ src,
        _Float16* __restrict__ XT) {
    int idx = blockIdx.x * 256 + threadIdx.x;   // b*2048+n
    int b = idx >> 11, n = idx & 2047;
    XT[((long)b * CC) * N_ + n] = (_Float16)src[((long)b * T_) * N_ + n];
}

// ---------------- D[n][c] = (1/1024) * sum_m A[n][m] * BT[c][m]; write DT[c][n] f16 ----------------
__device__ __forceinline__ f16x8 lds_frag(const _Float16* base, int r, int kb) {
    int byt = r * 128 + ((kb * 2) ^ ((r & 7) << 4));
    return *(const f16x8*)((const char*)base + byt);
}

__global__ __launch_bounds__(256) void k_gemm(const _Float16* __restrict__ A,
        const _Float16* __restrict__ BT, _Float16* __restrict__ DT) {
    __shared__ __align__(16) _Float16 As[2][64 * 64];
    __shared__ __align__(16) _Float16 Bs[2][64 * 64];
    int bm = blockIdx.x;
    int bc = blockIdx.y;
    int tid = threadIdx.x;
    int wid = tid >> 6, lane = tid & 63;
    int row_g = bm * 64, col_g = bc * 64;
    int r0 = (wid & 1) * 32, c0 = (wid >> 1) * 32;

    int lr8 = lane >> 3;
    int lsw = 8 * ((lane & 7) ^ lr8);
    long aoff[2], boff[2];
    int ldo[2];
#pragma unroll
    for (int i = 0; i < 2; ++i) {
        aoff[i] = (long)(row_g + wid * 16 + i * 8 + lr8) * N_ + lsw;
        boff[i] = (long)(col_g + wid * 16 + i * 8 + lr8) * N_ + lsw;
        ldo[i] = (wid * 16 + i * 8) * 64;
    }
    auto stage = [&](int buf, int kt) {
        int k0 = kt * 64;
#pragma unroll
        for (int i = 0; i < 2; ++i)
            __builtin_amdgcn_global_load_lds(
                (const __attribute__((address_space(1))) void*)(A + aoff[i] + k0),
                (__attribute__((address_space(3))) void*)&As[buf][ldo[i]], 16, 0, 0);
#pragma unroll
        for (int i = 0; i < 2; ++i)
            __builtin_amdgcn_global_load_lds(
                (const __attribute__((address_space(1))) void*)(BT + boff[i] + k0),
                (__attribute__((address_space(3))) void*)&Bs[buf][ldo[i]], 16, 0, 0);
    };

    f32x4 acc[2][2] = {};
    const int NT = 32;
    stage(0, 0);
    for (int kt = 0; kt < NT; ++kt) {
        int buf = kt & 1;
        if (kt + 1 < NT) {
            stage(buf ^ 1, kt + 1);
            asm volatile("s_waitcnt vmcnt(4)" ::: "memory");
        } else {
            asm volatile("s_waitcnt vmcnt(0)" ::: "memory");
        }
        __builtin_amdgcn_s_barrier();
        const _Float16* Ab = As[buf];
        const _Float16* Bb = Bs[buf];
#pragma unroll
        for (int kk = 0; kk < 64; kk += 32) {
            int kb = kk + (lane >> 4) * 8;
            f16x8 af0 = lds_frag(Ab, r0 + (lane & 15), kb);
            f16x8 af1 = lds_frag(Ab, r0 + 16 + (lane & 15), kb);
            f16x8 bf0 = lds_frag(Bb, c0 + (lane & 15), kb);
            f16x8 bf1 = lds_frag(Bb, c0 + 16 + (lane & 15), kb);
            acc[0][0] = __builtin_amdgcn_mfma_f32_16x16x32_f16(af0, bf0, acc[0][0], 0, 0, 0);
            acc[0][1] = __builtin_amdgcn_mfma_f32_16x16x32_f16(af0, bf1, acc[0][1], 0, 0, 0);
            acc[1][0] = __builtin_amdgcn_mfma_f32_16x16x32_f16(af1, bf0, acc[1][0], 0, 0, 0);
            acc[1][1] = __builtin_amdgcn_mfma_f32_16x16x32_f16(af1, bf1, acc[1][1], 0, 0, 0);
        }
        asm volatile("s_waitcnt lgkmcnt(0)" ::: "memory");
        __builtin_amdgcn_s_barrier();
    }
#pragma unroll
    for (int rt = 0; rt < 2; ++rt)
#pragma unroll
        for (int ct = 0; ct < 2; ++ct) {
            int cg = col_g + c0 + ct * 16 + (lane & 15);
            int ng = row_g + r0 + rt * 16 + ((lane >> 4) << 2);
            us4 pk;
#pragma unroll
            for (int q = 0; q < 4; ++q) pk[q] = __builtin_bit_cast(unsigned short, (_Float16)(acc[rt][ct][q] * AINV));
            *(us4*)(DT + (long)cg * N_ + ng) = pk;
        }
}

// ---------------- gate apply (MFMA): zr = sigmoid(xg . GwT + Gb); z,r; XT h-rows <- z*h ----------------
__global__ __launch_bounds__(256) void k_apply_gate(const float* __restrict__ src,
        const _Float16* __restrict__ h, const _Float16* __restrict__ Y1T,
        const _Float16* __restrict__ Y2T, const _Float16* __restrict__ GwT,
        const float* __restrict__ Gb, int t,
        _Float16* __restrict__ z, _Float16* __restrict__ r, _Float16* __restrict__ XT) {
    int n = blockIdx.x, tid = threadIdx.x, wid = tid >> 6, lane = tid & 63;
    __shared__ __align__(16) _Float16 xg[16][232];
    _Float16* xf = &xg[0][0];
    for (int idx = tid; idx < 16 * 232; idx += 256) xf[idx] = (_Float16)0.f;
    __syncthreads();
    for (int idx = tid; idx < 16 * KI; idx += 256) {
        int b = idx / KI, kk = idx % KI;
        int k = kk / CC, i = kk % CC;
        float ih = (i == 0) ? src[((long)b * T_ + t) * N_ + n]
                            : (float)h[((long)b * N_ + n) * DH + (i - 1)];
        float val;
        if (k == 0)      val = ih;
        else if (k == 1) val = (float)Y1T[(long)(b * CC + i) * N_ + n];
        else             val = 2.f * (float)Y2T[(long)(b * CC + i) * N_ + n] - ih;
        xg[b][kk] = (_Float16)val;
    }
    __syncthreads();
    const _Float16* Wp = GwT + (long)n * (128 * KP);
    int cl = lane & 15, k8 = (lane >> 4) * 8;
    f32x4 acc0 = {}, acc1 = {};
#pragma unroll
    for (int ks = 0; ks < 7; ++ks) {
        f16x8 af = *(const f16x8*)&xg[cl][ks * 32 + k8];
        f16x8 b0 = *(const f16x8*)(Wp + (wid * 32 + cl) * KP + ks * 32 + k8);
        f16x8 b1 = *(const f16x8*)(Wp + (wid * 32 + 16 + cl) * KP + ks * 32 + k8);
        acc0 = __builtin_amdgcn_mfma_f32_16x16x32_f16(af, b0, acc0, 0, 0, 0);
        acc1 = __builtin_amdgcn_mfma_f32_16x16x32_f16(af, b1, acc1, 0, 0, 0);
    }
#pragma unroll
    for (int tl = 0; tl < 2; ++tl) {
        f32x4 acc = tl ? acc1 : acc0;
        int o = wid * 32 + tl * 16 + cl;
        float bias = Gb[(long)n * 128 + o];
#pragma unroll
        for (int q = 0; q < 4; ++q) {
            int b = (lane >> 4) * 4 + q;
            float sv = 1.f / (1.f + __expf(-(acc[q] + bias)));
            long base = ((long)b * N_ + n) * DH;
            if (o < 64) {
                z[base + o] = (_Float16)sv;
                XT[(long)(b * CC + 1 + o) * N_ + n] = (_Float16)(sv * (float)h[base + o]);
            } else {
                r[base + (o - 64)] = (_Float16)sv;
            }
        }
    }
}

// ---------------- update apply (MFMA): hc=tanh(.); h=r*h+(1-r)*hc; states[t]; XT rows t+1 ----------------
__global__ __launch_bounds__(256) void k_apply_update(const float* __restrict__ src,
        _Float16* __restrict__ h, const _Float16* __restrict__ Y1T,
        const _Float16* __restrict__ Y2T, const _Float16* __restrict__ UwT,
        const float* __restrict__ Ub, const _Float16* __restrict__ z,
        const _Float16* __restrict__ rb, int t, _Float16* __restrict__ states,
        _Float16* __restrict__ XT) {
    int n = blockIdx.x, tid = threadIdx.x, wid = tid >> 6, lane = tid & 63;
    __shared__ __align__(16) _Float16 xg[16][232];
    _Float16* xf = &xg[0][0];
    for (int idx = tid; idx < 16 * 232; idx += 256) xf[idx] = (_Float16)0.f;
    __syncthreads();
    for (int idx = tid; idx < 16 * KI; idx += 256) {
        int b = idx / KI, kk = idx % KI;
        int k = kk / CC, i = kk % CC;
        float ih;
        if (i == 0) ih = src[((long)b * T_ + t) * N_ + n];
        else {
            long base = ((long)b * N_ + n) * DH + (i - 1);
            ih = (float)h[base] * (float)z[base];
        }
        float val;
        if (k == 0)      val = ih;
        else if (k == 1) val = (float)Y1T[(long)(b * CC + i) * N_ + n];
        else             val = 2.f * (float)Y2T[(long)(b * CC + i) * N_ + n] - ih;
        xg[b][kk] = (_Float16)val;
    }
    __syncthreads();
    const _Float16* Wp = UwT + (long)n * (64 * KP);
    int cl = lane & 15, k8 = (lane >> 4) * 8;
    f32x4 acc0 = {};
#pragma unroll
    for (int ks = 0; ks < 7; ++ks) {
        f16x8 af = *(const f16x8*)&xg[cl][ks * 32 + k8];
        f16x8 b0 = *(const f16x8*)(Wp + (wid * 16 + cl) * KP + ks * 32 + k8);
        acc0 = __builtin_amdgcn_mfma_f32_16x16x32_f16(af, b0, acc0, 0, 0, 0);
    }
    int o = wid * 16 + cl;
    float bias = Ub[(long)n * 64 + o];
#pragma unroll
    for (int q = 0; q < 4; ++q) {
        int b = (lane >> 4) * 4 + q;
        long base = ((long)b * N_ + n) * DH + o;
        float hc = tanhf(acc0[q] + bias);
        float rv = (float)rb[base], hv = (float)h[base];
        float hn = rv * hv + (1.f - rv) * hc;
        _Float16 hn16 = (_Float16)hn;
        h[base] = hn16;
        states[(((long)b * T_ + t) * N_ + n) * DH + o] = hn16;
        XT[(long)(b * CC + 1 + o) * N_ + n] = hn16;
        if (o == 0 && t + 1 < T_)
            XT[(long)(b * CC) * N_ + n] = (_Float16)src[((long)b * T_ + t + 1) * N_ + n];
    }
}

// ---------------- qkv projection (MFMA): KV for all t, Q at t=11 ----------------
__global__ __launch_bounds__(256) void k_qkv(const _Float16* __restrict__ st,
        const _Float16* __restrict__ Wi16, const float* __restrict__ bi,
        _Float16* __restrict__ KV, _Float16* __restrict__ Q) {
    int bt = blockIdx.x;        // b*12 + t
    int nck = blockIdx.y;       // n-chunk of 128
    int b = bt / 12, t = bt % 12;
    int tid = threadIdx.x, wid = tid >> 6, lane = tid & 63;
    __shared__ float pe[64];
    __shared__ __align__(16) _Float16 Xs[128][72];
    if (tid < 64) {
        int e = tid;
        float div = __powf(10000.f, -(float)(e & ~1) / 64.f);
        float ang = (float)t * div;
        pe[e] = (e & 1) ? __cosf(ang) : __sinf(ang);
    }
    __syncthreads();
    const _Float16* srcp = st + ((long)(b * T_ + t) * N_ + nck * 128) * DH;
#pragma unroll
    for (int u = 0; u < 4; ++u) {
        int idx = u * 256 + tid;
        int rr = idx >> 3, e0 = (idx & 7) * 8;
        f16x8 v = *(const f16x8*)(srcp + rr * DH + e0);
        f16x8 ov;
#pragma unroll
        for (int q = 0; q < 8; ++q) ov[q] = (_Float16)((float)v[q] + pe[e0 + q]);
        *(f16x8*)&Xs[rr][e0] = ov;
    }
    __syncthreads();
    int cl = lane & 15, ks8 = (lane >> 4) * 8;
    f16x8 bfrag[3][2];
    float bias[3];
#pragma unroll
    for (int j = 0; j < 3; ++j) {
        int c = (wid * 3 + j) * 16 + cl;
#pragma unroll
        for (int ks = 0; ks < 2; ++ks)
            bfrag[j][ks] = *(const f16x8*)(Wi16 + c * 64 + ks * 32 + ks8);
        bias[j] = bi[c];
    }
    f32x4 acc[8][3] = {};
#pragma unroll
    for (int rt = 0; rt < 8; ++rt) {
#pragma unroll
        for (int ks = 0; ks < 2; ++ks) {
            f16x8 af = *(const f16x8*)&Xs[rt * 16 + cl][ks * 32 + ks8];
#pragma unroll
            for (int j = 0; j < 3; ++j)
                acc[rt][j] = __builtin_amdgcn_mfma_f32_16x16x32_f16(af, bfrag[j][ks], acc[rt][j], 0, 0, 0);
        }
    }
    int rowq = (lane >> 4) * 4;
#pragma unroll
    for (int rt = 0; rt < 8; ++rt)
#pragma unroll
        for (int j = 0; j < 3; ++j) {
            int c = (wid * 3 + j) * 16 + cl;
#pragma unroll
            for (int q = 0; q < 4; ++q) {
                int n = nck * 128 + rt * 16 + rowq + q;
                float val = acc[rt][j][q] + bias[j];
                if (c >= 64)
                    KV[(((long)b * N_ + n) * T_ + t) * 128 + (c - 64)] = (_Float16)val;
                else if (t == 11)
                    Q[((long)b * N_ + n) * 64 + c] = (_Float16)val;
            }
        }
}

// ---------------- attention + out-proj: 16 pairs/block, 16 threads/pair ----------------
__global__ __launch_bounds__(256) void k_attn2(const _Float16* __restrict__ KV,
        const _Float16* __restrict__ Q, const _Float16* __restrict__ Wo16,
        const float* __restrict__ bo, float* __restrict__ o1) {
    __shared__ _Float16 kvs[16 * 1544];     // 12*128 + 8 pad per pair
    __shared__ float qs[16][64];
    __shared__ float Wos[64][64];           // [c][j]
    __shared__ float outb[16][64];
    __shared__ float bos[64];
    int tid = threadIdx.x;
    long pair0 = (long)blockIdx.x * 16;
#pragma unroll
    for (int u = 0; u < 12; ++u) {
        int idx = u * 256 + tid;
        int p = idx / 192, off8 = (idx % 192) * 8;
        *(f16x8*)&kvs[p * 1544 + off8] = *(const f16x8*)(KV + (pair0 + p) * 1536 + off8);
    }
    if (tid < 64) bos[tid] = bo[tid];
    for (int idx = tid; idx < 1024; idx += 256) {
        int p = idx >> 6, j = idx & 63;
        qs[p][j] = (float)Q[(pair0 + p) * 64 + j];
    }
    for (int idx = tid; idx < 4096; idx += 256) {
        int c = idx >> 6, j = idx & 63;
        Wos[c][j] = (float)Wo16[j * 64 + c];
    }
    __syncthreads();
    int p = tid >> 4, i = tid & 15;
    int h = i >> 2, sg = i & 3;
    const _Float16* kvp = &kvs[p * 1544];
    float att3[3], mx = -1e30f;
#pragma unroll
    for (int j = 0; j < 3; ++j) {
        int s = sg + 4 * j;
        float sc = 0.f;
#pragma unroll
        for (int d = 0; d < 16; ++d)
            sc = fmaf(qs[p][h * 16 + d], (float)kvp[s * 128 + h * 16 + d], sc);
        att3[j] = sc * 0.25f;
        mx = fmaxf(mx, att3[j]);
    }
    mx = fmaxf(mx, __shfl_xor(mx, 1));
    mx = fmaxf(mx, __shfl_xor(mx, 2));
    float se = 0.f;
#pragma unroll
    for (int j = 0; j < 3; ++j) { att3[j] = __expf(att3[j] - mx); se += att3[j]; }
    se += __shfl_xor(se, 1);
    se += __shfl_xor(se, 2);
    float inv = 1.f / se;
#pragma unroll
    for (int j = 0; j < 3; ++j) att3[j] *= inv;
    int c0 = i * 4;
    float out4[4] = {0.f, 0.f, 0.f, 0.f};
#pragma unroll
    for (int m = 0; m < 4; ++m) {
        float a0 = __shfl_xor(att3[0], m);
        float a1 = __shfl_xor(att3[1], m);
        float a2 = __shfl_xor(att3[2], m);
        int sb = sg ^ m;
        float aj[3] = {a0, a1, a2};
#pragma unroll
        for (int j = 0; j < 3; ++j) {
            int s = sb + 4 * j;
            f16x4 vv = *(const f16x4*)&kvp[s * 128 + 64 + c0];
#pragma unroll
            for (int q = 0; q < 4; ++q) out4[q] = fmaf(aj[j], (float)vv[q], out4[q]);
        }
    }
    *(float4*)&outb[p][c0] = *(float4*)out4;
    __syncthreads();
    float res[4];
#pragma unroll
    for (int q = 0; q < 4; ++q) res[q] = bos[c0 + q];
    for (int c = 0; c < 64; ++c) {
        float oc = outb[p][c];
        float4 wv = *(const float4*)&Wos[c][c0];
        res[0] = fmaf(oc, wv.x, res[0]);
        res[1] = fmaf(oc, wv.y, res[1]);
        res[2] = fmaf(oc, wv.z, res[2]);
        res[3] = fmaf(oc, wv.w, res[3]);
    }
    *(float4*)&o1[(pair0 + p) * 64 + c0] = make_float4(res[0], res[1], res[2], res[3]);
}

// ---------------- output head ----------------
__global__ __launch_bounds__(256) void k_final(const float* __restrict__ o1,
        const _Float16* __restrict__ hT, const float* __restrict__ cw,
        const float* __restrict__ convw, const float* __restrict__ convb,
        float* __restrict__ out) {
    __shared__ float Ws[12 * 3 * 64];
    __shared__ float cbs[12];
    int tid = threadIdx.x;
    for (int idx = tid; idx < 12 * 3 * 64; idx += 256) Ws[idx] = convw[idx];
    if (tid < 12) cbs[tid] = convb[tid];
    __syncthreads();
    float c0 = cw[0], c1 = cw[1], c2 = cw[2];
    int g = tid >> 6, j = tid & 63;
    int bn = blockIdx.x * 4 + g;
    int b = bn >> 11, n = bn & 2047;
    float x1 = o1[(long)bn * DH + j];
    float x3 = (float)hT[(long)bn * DH + j];
    float myout = 0.f;
#pragma unroll
    for (int oc = 0; oc < 12; ++oc) {
        float p = x1 * c0 * Ws[(oc * 3 + 0) * 64 + j]
                + x3 * (c1 * Ws[(oc * 3 + 1) * 64 + j] + c2 * Ws[(oc * 3 + 2) * 64 + j]);
        p += __shfl_xor(p, 1); p += __shfl_xor(p, 2); p += __shfl_xor(p, 4);
        p += __shfl_xor(p, 8); p += __shfl_xor(p, 16); p += __shfl_xor(p, 32);
        if (j == oc) myout = p + cbs[oc];
    }
    if (j < 12) out[((long)b * 12 + j) * N_ + n] = myout;
}

extern "C" void kernel_launch(void* const* d_in, const int* in_sizes, int n_in,
                              void* d_out, int out_size, void* d_ws, size_t ws_size,
                              hipStream_t stream) {
    const float* src    = (const float*)d_in[0];
    const float* emb    = (const float*)d_in[2];
    const float* gate_w = (const float*)d_in[3];
    const float* gate_b = (const float*)d_in[4];
    const float* upd_w  = (const float*)d_in[5];
    const float* upd_b  = (const float*)d_in[6];
    const float* a_in_w = (const float*)d_in[7];
    const float* a_in_b = (const float*)d_in[8];
    const float* a_out_w= (const float*)d_in[9];
    const float* a_out_b= (const float*)d_in[10];
    const float* chan_w = (const float*)d_in[11];
    const float* conv_w = (const float*)d_in[12];
    const float* conv_b = (const float*)d_in[13];
    float* out = (float*)d_out;

    char* ws = (char*)d_ws;
    size_t off = 0;
    auto alloc = [&](size_t bytes) { char* p = ws + off; off += (bytes + 255) & ~size_t(255); return p; };
    _Float16* A    = (_Float16*)alloc((size_t)N_ * N_ * 2);
    _Float16* GwT  = (_Float16*)alloc((size_t)N_ * 128 * KP * 2 + 256);   // +256B zero guard
    float*  Gb     = (float*) alloc((size_t)N_ * 128 * 4);
    _Float16* UwT  = (_Float16*)alloc((size_t)N_ * 64 * KP * 2 + 256);    // +256B zero guard
    float*  Ub     = (float*) alloc((size_t)N_ * 64 * 4);
    _Float16* XT   = (_Float16*)alloc((size_t)NCP * N_ * 2);
    _Float16* Y1T  = (_Float16*)alloc((size_t)NCP * N_ * 2);
    _Float16* Y2T  = (_Float16*)alloc((size_t)NCP * N_ * 2);
    _Float16* h    = (_Float16*)alloc((size_t)B_ * N_ * DH * 2);
    _Float16* zbuf = (_Float16*)alloc((size_t)B_ * N_ * DH * 2);
    _Float16* rbuf = (_Float16*)alloc((size_t)B_ * N_ * DH * 2);
    _Float16* stt  = (_Float16*)alloc((size_t)B_ * T_ * N_ * DH * 2);
    _Float16* Wi16 = (_Float16*)alloc(192 * 64 * 2);
    _Float16* Wo16 = (_Float16*)alloc(64 * 64 * 2);
    if (off > ws_size) return;   // ~243.5 MB total

    // dead-region aliases for post-GRU phase
    _Float16* KV = GwT;                            // 100.7 MB into GwT's 104.9 MB
    _Float16* Qb = UwT;                            // 4.2 MB at UwT start
    float*    o1 = (float*)((char*)UwT + (8u << 20)); // 8.4 MB at UwT+8MB (UwT dead, past Qb)

    hipMemsetAsync(h, 0, (size_t)B_ * N_ * DH * 2, stream);
    hipMemsetAsync(XT, 0, (size_t)NCP * N_ * 2, stream);
    // zero the overlap guards past the last weight row (MFMA K-tail reads them; 0 x 0 = 0)
    hipMemsetAsync(GwT + (size_t)N_ * 128 * KP, 0, 256, stream);
    hipMemsetAsync(UwT + (size_t)N_ * 64 * KP, 0, 256, stream);
    k_compA<<<N_, 256, 0, stream>>>(emb, A);
    k_build<<<1552, 256, 0, stream>>>(emb, gate_w, gate_b, upd_w, upd_b, GwT, Gb, UwT, Ub);
    k_wcvt<<<48, 256, 0, stream>>>(a_in_w, a_out_w, Wi16, Wo16);
    k_initx<<<128, 256, 0, stream>>>(src, XT);

    dim3 ggrid(32, 17);
    for (int t = 0; t < T_; ++t) {
        k_gemm<<<ggrid, 256, 0, stream>>>(A, XT, Y1T);
        k_gemm<<<ggrid, 256, 0, stream>>>(A, Y1T, Y2T);
        k_apply_gate<<<N_, 256, 0, stream>>>(src, h, Y1T, Y2T, GwT, Gb, t, zbuf, rbuf, XT);
        k_gemm<<<ggrid, 256, 0, stream>>>(A, XT, Y1T);
        k_gemm<<<ggrid, 256, 0, stream>>>(A, Y1T, Y2T);
        k_apply_update<<<N_, 256, 0, stream>>>(src, h, Y1T, Y2T, UwT, Ub, zbuf, rbuf, t, stt, XT);
    }
    dim3 qgrid(192, 16);
    k_qkv<<<qgrid, 256, 0, stream>>>(stt, Wi16, a_in_b, KV, Qb);
    k_attn2<<<2048, 256, 0, stream>>>(KV, Qb, Wo16, a_out_b, o1);
    k_final<<<8192, 256, 0, stream>>>(o1, h, chan_w, conv_w, conv_b, out);
}